// Round 3
// baseline (3257.693 us; speedup 1.0000x reference)
//
#include <hip/hip_runtime.h>
#include <hip/hip_bf16.h>

#define NN 50000
#define EE 800000
#define EP 850000   // EE + NN self-loops
#define DD 128

__device__ __forceinline__ float bf2f(__hip_bfloat16 x){ return __bfloat162float(x); }
// load float tensor element i, dtype selected at runtime (f32 ? float : bf16)
__device__ __forceinline__ float ldf(const void* p, size_t i, int f32){
  return f32 ? ((const float*)p)[i] : bf2f(((const __hip_bfloat16*)p)[i]);
}

// order-preserving float->uint encoding for atomicMax
__device__ __forceinline__ unsigned encf(float f){
  unsigned u = __float_as_uint(f);
  return (u & 0x80000000u) ? ~u : (u | 0x80000000u);
}
__device__ __forceinline__ float decf(unsigned e){
  return (e & 0x80000000u) ? __uint_as_float(e & 0x7fffffffu) : __uint_as_float(~e);
}

// ---------------- dtype probe: f32 storage read as bf16 shows NaN/Inf exponents ----------------
__global__ void probe_kernel(const unsigned short* __restrict__ xu, int* __restrict__ flag)
{
  __shared__ int sc[256];
  int c = 0;
  for (int i = threadIdx.x; i < 32768; i += 256)
    if ((xu[i] & 0x7F80) == 0x7F80) c++;      // bf16 inf/nan exponent pattern
  sc[threadIdx.x] = c;
  __syncthreads();
  for (int s = 128; s > 0; s >>= 1){
    if (threadIdx.x < s) sc[threadIdx.x] += sc[threadIdx.x + s];
    __syncthreads();
  }
  if (threadIdx.x == 0) flag[0] = (sc[0] > 16) ? 1 : 0;   // 1 => tensors are float32
}

// ---------------- GEMM: Hout[n][c] = sum_k X[n][k]*W[k][c], bf16 out ----------------
// XFOLLOW: x uses probed input dtype; otherwise x is internal f32 (accF).
template<bool XFOLLOW>
__global__ void __launch_bounds__(256) gemm_kernel(const void* __restrict__ Xv,
                                                   const void* __restrict__ Wv,
                                                   __hip_bfloat16* __restrict__ Hout,
                                                   const int* __restrict__ flag)
{
  const int f  = flag[0];
  const int xf = XFOLLOW ? f : 1;
  __shared__ float xs[128][68];   // [k][r], pad 68 keeps float4 alignment
  const int tid  = threadIdx.x;
  const int row0 = blockIdx.x * 64;
  #pragma unroll
  for (int i = 0; i < 32; i++){
    int idx = tid + i*256;
    int r = idx >> 7, k = idx & 127;
    int row = row0 + r;
    xs[k][r] = (row < NN) ? ldf(Xv, (size_t)row*DD + k, xf) : 0.f;
  }
  __syncthreads();

  const int cg = tid & 31, rg = tid >> 5;
  const int c0 = cg*4,    r0 = rg*8;
  float acc[8][4];
  #pragma unroll
  for (int i=0;i<8;i++){ acc[i][0]=0.f; acc[i][1]=0.f; acc[i][2]=0.f; acc[i][3]=0.f; }

  #pragma unroll 4
  for (int k = 0; k < 128; k++){
    float w0 = ldf(Wv, (size_t)k*DD + c0 + 0, f);
    float w1 = ldf(Wv, (size_t)k*DD + c0 + 1, f);
    float w2 = ldf(Wv, (size_t)k*DD + c0 + 2, f);
    float w3 = ldf(Wv, (size_t)k*DD + c0 + 3, f);
    const float4 xa = *(const float4*)&xs[k][r0];
    const float4 xb = *(const float4*)&xs[k][r0+4];
    acc[0][0] += xa.x*w0; acc[0][1] += xa.x*w1; acc[0][2] += xa.x*w2; acc[0][3] += xa.x*w3;
    acc[1][0] += xa.y*w0; acc[1][1] += xa.y*w1; acc[1][2] += xa.y*w2; acc[1][3] += xa.y*w3;
    acc[2][0] += xa.z*w0; acc[2][1] += xa.z*w1; acc[2][2] += xa.z*w2; acc[2][3] += xa.z*w3;
    acc[3][0] += xa.w*w0; acc[3][1] += xa.w*w1; acc[3][2] += xa.w*w2; acc[3][3] += xa.w*w3;
    acc[4][0] += xb.x*w0; acc[4][1] += xb.x*w1; acc[4][2] += xb.x*w2; acc[4][3] += xb.x*w3;
    acc[5][0] += xb.y*w0; acc[5][1] += xb.y*w1; acc[5][2] += xb.y*w2; acc[5][3] += xb.y*w3;
    acc[6][0] += xb.z*w0; acc[6][1] += xb.z*w1; acc[6][2] += xb.z*w2; acc[6][3] += xb.z*w3;
    acc[7][0] += xb.w*w0; acc[7][1] += xb.w*w1; acc[7][2] += xb.w*w2; acc[7][3] += xb.w*w3;
  }
  #pragma unroll
  for (int i = 0; i < 8; i++){
    int row = row0 + r0 + i;
    if (row < NN){
      __hip_bfloat16 o[4];
      o[0] = __float2bfloat16(acc[i][0]);
      o[1] = __float2bfloat16(acc[i][1]);
      o[2] = __float2bfloat16(acc[i][2]);
      o[3] = __float2bfloat16(acc[i][3]);
      *(uint2*)&Hout[(size_t)row*DD + c0] = *(const uint2*)o;
    }
  }
}

// ---------------- per-(node,head) attention scalars ----------------
template<int H>
__global__ void __launch_bounds__(256) al_kernel(const __hip_bfloat16* __restrict__ hB,
    const void* __restrict__ a_s, const void* __restrict__ a_d,
    float* __restrict__ alS, float* __restrict__ alD, const int* __restrict__ flag)
{
  const int f = flag[0];
  const int C = DD / H;
  int gid = blockIdx.x*256 + threadIdx.x;
  if (gid >= NN*H) return;
  int n = gid / H, hd = gid % H;
  float ps = 0.f, pd = 0.f;
  #pragma unroll
  for (int c = 0; c < C; c++){
    float hv = bf2f(hB[(size_t)n*DD + hd*C + c]);
    ps += hv * ldf(a_s, hd*C + c, f);
    pd += hv * ldf(a_d, hd*C + c, f);
  }
  alS[gid] = ps;
  alD[gid] = pd;
}

// ---------------- init acc/m/s (ws is poisoned every launch) ----------------
__global__ void __launch_bounds__(256) init_kernel(float* __restrict__ outAcc,
    unsigned* __restrict__ mEnc, float* __restrict__ sSum, int hTot)
{
  int i = blockIdx.x*256 + threadIdx.x;   // grid covers NN*DD exactly
  outAcc[i] = 0.f;
  if (i < hTot){ mEnc[i] = 0u; sSum[i] = 0.f; }
}

// ---------------- edge pass 1: segment max ----------------
template<int H>
__global__ void __launch_bounds__(256) edge_max_kernel(const int* __restrict__ ei,
    const float* __restrict__ alS, const float* __restrict__ alD, unsigned* __restrict__ mEnc)
{
  int e = blockIdx.x*256 + threadIdx.x;
  if (e >= EP) return;
  int s, d;
  if (e < EE){ s = ei[e]; d = ei[EE + e]; } else { s = d = e - EE; }
  #pragma unroll
  for (int hd = 0; hd < H; hd++){
    float el = alS[s*H + hd] + alD[d*H + hd];
    el = el > 0.f ? el : 0.2f*el;
    atomicMax(&mEnc[d*H + hd], encf(el));
  }
}

// ---------------- edge pass 2: segment sum of exp ----------------
template<int H>
__global__ void __launch_bounds__(256) edge_expsum_kernel(const int* __restrict__ ei,
    const float* __restrict__ alS, const float* __restrict__ alD,
    const unsigned* __restrict__ mEnc, float* __restrict__ sSum)
{
  int e = blockIdx.x*256 + threadIdx.x;
  if (e >= EP) return;
  int s, d;
  if (e < EE){ s = ei[e]; d = ei[EE + e]; } else { s = d = e - EE; }
  #pragma unroll
  for (int hd = 0; hd < H; hd++){
    float el = alS[s*H + hd] + alD[d*H + hd];
    el = el > 0.f ? el : 0.2f*el;
    float ex = __expf(el - decf(mEnc[d*H + hd]));
    unsafeAtomicAdd(&sSum[d*H + hd], ex);
  }
}

// ---------------- edge pass 3: weighted aggregation ----------------
template<int H, int CSHIFT>
__global__ void __launch_bounds__(256) edge_agg_kernel(const int* __restrict__ ei,
    const float* __restrict__ alS, const float* __restrict__ alD,
    const unsigned* __restrict__ mEnc, const float* __restrict__ sSum,
    const __hip_bfloat16* __restrict__ Hm, float* __restrict__ outAcc)
{
  __shared__ float alf[2*H];
  const int tid = threadIdx.x;
  const int e0  = blockIdx.x*2;
  if (tid < 2*H){
    int sub = tid / H, hd = tid % H;
    int e = e0 + sub;
    int s, d;
    if (e < EE){ s = ei[e]; d = ei[EE + e]; } else { s = d = e - EE; }
    float el = alS[s*H + hd] + alD[d*H + hd];
    el = el > 0.f ? el : 0.2f*el;
    float m = decf(mEnc[d*H + hd]);
    alf[tid] = __expf(el - m) / fmaxf(sSum[d*H + hd], 1e-30f);
  }
  __syncthreads();
  int sub = tid >> 7, c = tid & 127;
  int e = e0 + sub;
  int s, d;
  if (e < EE){ s = ei[e]; d = ei[EE + e]; } else { s = d = e - EE; }
  float v = bf2f(Hm[(size_t)s*DD + c]) * alf[sub*H + (c >> CSHIFT)];
  unsafeAtomicAdd(&outAcc[(size_t)d*DD + c], v);
}

// ---------------- bias + LayerNorm (+ELU); final write branches on dtype ----------------
template<bool FINAL>
__global__ void __launch_bounds__(256) ln_kernel(const float* __restrict__ acc,
    const void* __restrict__ b, const void* __restrict__ g, const void* __restrict__ be,
    float* __restrict__ xNext, void* __restrict__ outv, const int* __restrict__ flag)
{
  const int f = flag[0];
  int row  = blockIdx.x*4 + (threadIdx.x >> 6);
  int lane = threadIdx.x & 63;
  float v0 = acc[(size_t)row*DD + lane]      + ldf(b, lane, f);
  float v1 = acc[(size_t)row*DD + 64 + lane] + ldf(b, 64+lane, f);
  float s = v0 + v1;
  #pragma unroll
  for (int off = 32; off >= 1; off >>= 1) s += __shfl_xor(s, off, 64);
  float mu = s * (1.0f/128.0f);
  float d0 = v0 - mu, d1 = v1 - mu;
  float q = d0*d0 + d1*d1;
  #pragma unroll
  for (int off = 32; off >= 1; off >>= 1) q += __shfl_xor(q, off, 64);
  float r = rsqrtf(q*(1.0f/128.0f) + 1e-5f);
  float y0 = d0*r*ldf(g, lane, f)    + ldf(be, lane, f);
  float y1 = d1*r*ldf(g, 64+lane, f) + ldf(be, 64+lane, f);
  if (FINAL){
    if (f){
      ((float*)outv)[(size_t)row*DD + lane]      = y0;
      ((float*)outv)[(size_t)row*DD + 64 + lane] = y1;
    } else {
      ((__hip_bfloat16*)outv)[(size_t)row*DD + lane]      = __float2bfloat16(y0);
      ((__hip_bfloat16*)outv)[(size_t)row*DD + 64 + lane] = __float2bfloat16(y1);
    }
  } else {
    xNext[(size_t)row*DD + lane]      = y0 > 0.f ? y0 : __expf(y0) - 1.f;
    xNext[(size_t)row*DD + 64 + lane] = y1 > 0.f ? y1 : __expf(y1) - 1.f;
  }
}

// ---------------- host-side layer driver ----------------
template<bool XFOLLOW, int H, int CSHIFT, bool FINAL>
static void run_layer(const void* x, const void* W,
                      const void* a_s, const void* a_d,
                      const void* b, const void* g, const void* be,
                      const int* ei,
                      __hip_bfloat16* hB, float* accF, float* alS, float* alD,
                      unsigned* mEnc, float* sSum, const int* flag,
                      void* outv, hipStream_t stream)
{
  gemm_kernel<XFOLLOW><<<782, 256, 0, stream>>>(x, W, hB, flag);
  al_kernel<H><<<(NN*H + 255)/256, 256, 0, stream>>>(hB, a_s, a_d, alS, alD, flag);
  init_kernel<<<25000, 256, 0, stream>>>(accF, mEnc, sSum, NN*H);
  edge_max_kernel<H><<<(EP + 255)/256, 256, 0, stream>>>(ei, alS, alD, mEnc);
  edge_expsum_kernel<H><<<(EP + 255)/256, 256, 0, stream>>>(ei, alS, alD, mEnc, sSum);
  edge_agg_kernel<H, CSHIFT><<<EP/2, 256, 0, stream>>>(ei, alS, alD, mEnc, sSum, hB, accF);
  ln_kernel<FINAL><<<12500, 256, 0, stream>>>(accF, b, g, be, accF, outv, flag);
}

extern "C" void kernel_launch(void* const* d_in, const int* in_sizes, int n_in,
                              void* d_out, int out_size, void* d_ws, size_t ws_size,
                              hipStream_t stream)
{
  // ws layout: 256B header (flag) | accF 25.6MB | alS/alD/sSum/mEnc 1.6MB each
  const size_t need = 256 + (size_t)NN*DD*4 + 4*(size_t)NN*8*4;
  if (ws_size < need) return;   // diagnostic fallback: finite absmax instead of corruption

  int*   flag = (int*)d_ws;
  float* accF = (float*)((char*)d_ws + 256);         // NN*DD f32
  float* alS  = accF + (size_t)NN*DD;                // NN*8
  float* alD  = alS  + (size_t)NN*8;
  float* sSum = alD  + (size_t)NN*8;
  unsigned* mEnc = (unsigned*)(sSum + (size_t)NN*8);

  const void* x  = d_in[0];
  const int*  ei = (const int*)d_in[1];
  const void *W0=d_in[2], *as0=d_in[3], *ad0=d_in[4], *b0=d_in[5], *g0=d_in[6], *be0=d_in[7];
  const void *W1=d_in[8], *as1=d_in[9], *ad1=d_in[10],*b1=d_in[11],*g1=d_in[12],*be1=d_in[13];
  const void *W2=d_in[14],*as2=d_in[15],*ad2=d_in[16],*b2=d_in[17],*g2=d_in[18],*be2=d_in[19];

  __hip_bfloat16* hB = (__hip_bfloat16*)d_out;   // h staged in d_out (bf16, 12.8MB fits both modes)

  probe_kernel<<<1, 256, 0, stream>>>((const unsigned short*)x, flag);

  // layer 0: x = probed dtype, 8 heads
  run_layer<true, 8, 4, false>(x,    W0, as0, ad0, b0, g0, be0, ei,
                               hB, accF, alS, alD, mEnc, sSum, flag, d_out, stream);
  // layer 1: x = internal f32 (accF), 8 heads
  run_layer<false, 8, 4, false>(accF, W1, as1, ad1, b1, g1, be1, ei,
                               hB, accF, alS, alD, mEnc, sSum, flag, d_out, stream);
  // layer 2: x = internal f32, 1 head, final (dtype-adaptive write to d_out)
  run_layer<false, 1, 7, true>(accF, W2, as2, ad2, b2, g2, be2, ei,
                               hB, accF, alS, alD, mEnc, sSum, flag, d_out, stream);
}

// Round 4
// 1334.634 us; speedup vs baseline: 2.4409x; 2.4409x over previous
//
#include <hip/hip_runtime.h>
#include <hip/hip_bf16.h>

#define NN 50000
#define EE 800000
#define EP 850000   // EE + NN self-loops
#define DD 128

__device__ __forceinline__ float bf2f(__hip_bfloat16 x){ return __bfloat162float(x); }
__device__ __forceinline__ float bfu(unsigned short u){ return __uint_as_float(((unsigned)u)<<16); }
// load float tensor element i, dtype selected at runtime (f32 ? float : bf16)
__device__ __forceinline__ float ldf(const void* p, size_t i, int f32){
  return f32 ? ((const float*)p)[i] : bf2f(((const __hip_bfloat16*)p)[i]);
}

// ---------------- dtype probe: f32 storage read as bf16 shows NaN/Inf exponents ----------------
__global__ void probe_kernel(const unsigned short* __restrict__ xu, int* __restrict__ flag)
{
  __shared__ int sc[256];
  int c = 0;
  for (int i = threadIdx.x; i < 32768; i += 256)
    if ((xu[i] & 0x7F80) == 0x7F80) c++;
  sc[threadIdx.x] = c;
  __syncthreads();
  for (int s = 128; s > 0; s >>= 1){
    if (threadIdx.x < s) sc[threadIdx.x] += sc[threadIdx.x + s];
    __syncthreads();
  }
  if (threadIdx.x == 0) flag[0] = (sc[0] > 16) ? 1 : 0;   // 1 => tensors are float32
}

// ---------------- CSR build ----------------
__global__ void __launch_bounds__(256) zero_deg_kernel(int* __restrict__ deg)
{
  int i = blockIdx.x*256 + threadIdx.x;
  if (i < NN) deg[i] = 0;
}

__global__ void __launch_bounds__(256) hist_kernel(const int* __restrict__ ei, int* __restrict__ deg)
{
  int e = blockIdx.x*256 + threadIdx.x;
  if (e >= EP) return;
  int d = (e < EE) ? ei[EE + e] : e - EE;
  atomicAdd(&deg[d], 1);
}

// single-block exclusive scan of deg -> rowStart (and cursor copy)
__global__ void __launch_bounds__(1024) scan_kernel(const int* __restrict__ deg,
    int* __restrict__ rowStart, int* __restrict__ cursor)
{
  __shared__ int buf[1024];
  __shared__ int carryS;
  const int tid = threadIdx.x;
  if (tid == 0) carryS = 0;
  __syncthreads();
  for (int base = 0; base < NN; base += 1024){
    int c0 = carryS;
    int i = base + tid;
    int v = (i < NN) ? deg[i] : 0;
    buf[tid] = v;
    __syncthreads();
    for (int off = 1; off < 1024; off <<= 1){
      int t = (tid >= off) ? buf[tid - off] : 0;
      __syncthreads();
      buf[tid] += t;
      __syncthreads();
    }
    int excl = buf[tid] - v + c0;
    if (i < NN){ rowStart[i] = excl; cursor[i] = excl; }
    __syncthreads();
    if (tid == 0) carryS = c0 + buf[1023];
    __syncthreads();
  }
  if (tid == 0) rowStart[NN] = carryS;   // == EP
}

__global__ void __launch_bounds__(256) scatter_kernel(const int* __restrict__ ei,
    int* __restrict__ cursor, unsigned short* __restrict__ srcL)
{
  int e = blockIdx.x*256 + threadIdx.x;
  if (e >= EP) return;
  int s, d;
  if (e < EE){ s = ei[e]; d = ei[EE + e]; } else { s = d = e - EE; }
  int pos = atomicAdd(&cursor[d], 1);
  srcL[pos] = (unsigned short)s;
}

// ---------------- GEMM: Hout[n][c] = sum_k X[n][k]*W[k][c], bf16 out ----------------
template<bool XFOLLOW>
__global__ void __launch_bounds__(256) gemm_kernel(const void* __restrict__ Xv,
                                                   const void* __restrict__ Wv,
                                                   __hip_bfloat16* __restrict__ Hout,
                                                   const int* __restrict__ flag)
{
  const int f  = flag[0];
  const int xf = XFOLLOW ? f : 1;
  __shared__ float xs[128][68];
  const int tid  = threadIdx.x;
  const int row0 = blockIdx.x * 64;
  #pragma unroll
  for (int i = 0; i < 32; i++){
    int idx = tid + i*256;
    int r = idx >> 7, k = idx & 127;
    int row = row0 + r;
    xs[k][r] = (row < NN) ? ldf(Xv, (size_t)row*DD + k, xf) : 0.f;
  }
  __syncthreads();

  const int cg = tid & 31, rg = tid >> 5;
  const int c0 = cg*4,    r0 = rg*8;
  float acc[8][4];
  #pragma unroll
  for (int i=0;i<8;i++){ acc[i][0]=0.f; acc[i][1]=0.f; acc[i][2]=0.f; acc[i][3]=0.f; }

  #pragma unroll 4
  for (int k = 0; k < 128; k++){
    float w0 = ldf(Wv, (size_t)k*DD + c0 + 0, f);
    float w1 = ldf(Wv, (size_t)k*DD + c0 + 1, f);
    float w2 = ldf(Wv, (size_t)k*DD + c0 + 2, f);
    float w3 = ldf(Wv, (size_t)k*DD + c0 + 3, f);
    const float4 xa = *(const float4*)&xs[k][r0];
    const float4 xb = *(const float4*)&xs[k][r0+4];
    acc[0][0] += xa.x*w0; acc[0][1] += xa.x*w1; acc[0][2] += xa.x*w2; acc[0][3] += xa.x*w3;
    acc[1][0] += xa.y*w0; acc[1][1] += xa.y*w1; acc[1][2] += xa.y*w2; acc[1][3] += xa.y*w3;
    acc[2][0] += xa.z*w0; acc[2][1] += xa.z*w1; acc[2][2] += xa.z*w2; acc[2][3] += xa.z*w3;
    acc[3][0] += xa.w*w0; acc[3][1] += xa.w*w1; acc[3][2] += xa.w*w2; acc[3][3] += xa.w*w3;
    acc[4][0] += xb.x*w0; acc[4][1] += xb.x*w1; acc[4][2] += xb.x*w2; acc[4][3] += xb.x*w3;
    acc[5][0] += xb.y*w0; acc[5][1] += xb.y*w1; acc[5][2] += xb.y*w2; acc[5][3] += xb.y*w3;
    acc[6][0] += xb.z*w0; acc[6][1] += xb.z*w1; acc[6][2] += xb.z*w2; acc[6][3] += xb.z*w3;
    acc[7][0] += xb.w*w0; acc[7][1] += xb.w*w1; acc[7][2] += xb.w*w2; acc[7][3] += xb.w*w3;
  }
  #pragma unroll
  for (int i = 0; i < 8; i++){
    int row = row0 + r0 + i;
    if (row < NN){
      __hip_bfloat16 o[4];
      o[0] = __float2bfloat16(acc[i][0]);
      o[1] = __float2bfloat16(acc[i][1]);
      o[2] = __float2bfloat16(acc[i][2]);
      o[3] = __float2bfloat16(acc[i][3]);
      *(uint2*)&Hout[(size_t)row*DD + c0] = *(const uint2*)o;
    }
  }
}

// ---------------- per-(node,head) attention scalars ----------------
template<int H>
__global__ void __launch_bounds__(256) al_kernel(const __hip_bfloat16* __restrict__ hB,
    const void* __restrict__ a_s, const void* __restrict__ a_d,
    float* __restrict__ alS, float* __restrict__ alD, const int* __restrict__ flag)
{
  const int f = flag[0];
  const int C = DD / H;
  int gid = blockIdx.x*256 + threadIdx.x;
  if (gid >= NN*H) return;
  int n = gid / H, hd = gid % H;
  float ps = 0.f, pd = 0.f;
  #pragma unroll
  for (int c = 0; c < C; c++){
    float hv = bf2f(hB[(size_t)n*DD + hd*C + c]);
    ps += hv * ldf(a_s, hd*C + c, f);
    pd += hv * ldf(a_d, hd*C + c, f);
  }
  alS[gid] = ps;
  alD[gid] = pd;
}

// ---------------- fused: per-dst softmax + gather-aggregate + bias + LN (+ELU) ----------------
// one wave per dst node; lane covers channels 2*lane, 2*lane+1
template<int H, bool ELU>
__global__ void __launch_bounds__(256) aggln_kernel(
    const int* __restrict__ rowStart, const unsigned short* __restrict__ srcL,
    const float* __restrict__ alS, const float* __restrict__ alD,
    const __hip_bfloat16* __restrict__ hB,
    const void* __restrict__ b, const void* __restrict__ g, const void* __restrict__ be,
    float* __restrict__ outF, const int* __restrict__ flag)
{
  const int f    = flag[0];
  const int lane = threadIdx.x & 63;
  const int d    = blockIdx.x*4 + (threadIdx.x >> 6);
  const int C    = DD / H;
  const int c0   = lane*2;
  const int hd   = c0 / C;
  const int start = rowStart[d], end = rowStart[d+1];
  const float aldv = alD[d*H + hd];

  float m = -1e30f;
  for (int i = start; i < end; i++){
    int s = srcL[i];
    float el = alS[s*H + hd] + aldv;
    el = el > 0.f ? el : 0.2f*el;
    m = fmaxf(m, el);
  }
  float ssum = 0.f;
  for (int i = start; i < end; i++){
    int s = srcL[i];
    float el = alS[s*H + hd] + aldv;
    el = el > 0.f ? el : 0.2f*el;
    ssum += __expf(el - m);
  }
  const float sinv = 1.f / ssum;   // >= 1 guaranteed (self-loop contributes exp(0))
  float a0 = 0.f, a1 = 0.f;
  for (int i = start; i < end; i++){
    int s = srcL[i];
    float el = alS[s*H + hd] + aldv;
    el = el > 0.f ? el : 0.2f*el;
    float alpha = __expf(el - m) * sinv;
    ushort2 hv = *(const ushort2*)&hB[(size_t)s*DD + c0];
    a0 = fmaf(bfu(hv.x), alpha, a0);
    a1 = fmaf(bfu(hv.y), alpha, a1);
  }

  // bias + LayerNorm across the wave's 128 channels
  float v0 = a0 + ldf(b, c0, f), v1 = a1 + ldf(b, c0+1, f);
  float s2 = v0 + v1;
  #pragma unroll
  for (int off = 32; off >= 1; off >>= 1) s2 += __shfl_xor(s2, off, 64);
  float mu = s2 * (1.0f/128.0f);
  float d0 = v0 - mu, d1 = v1 - mu;
  float q = d0*d0 + d1*d1;
  #pragma unroll
  for (int off = 32; off >= 1; off >>= 1) q += __shfl_xor(q, off, 64);
  float r = rsqrtf(q*(1.0f/128.0f) + 1e-5f);
  float y0 = d0*r*ldf(g, c0, f)   + ldf(be, c0, f);
  float y1 = d1*r*ldf(g, c0+1, f) + ldf(be, c0+1, f);
  if (ELU){
    y0 = y0 > 0.f ? y0 : __expf(y0) - 1.f;
    y1 = y1 > 0.f ? y1 : __expf(y1) - 1.f;
  }
  float2 o = make_float2(y0, y1);
  *(float2*)&outF[(size_t)d*DD + c0] = o;
}

// ---------------- final convert accF -> d_out (dtype per flag) ----------------
__global__ void __launch_bounds__(256) conv_kernel(const float* __restrict__ acc,
    void* __restrict__ outv, const int* __restrict__ flag)
{
  int i = blockIdx.x*256 + threadIdx.x;   // grid covers NN*DD exactly
  float v = acc[i];
  if (flag[0]) ((float*)outv)[i] = v;
  else ((__hip_bfloat16*)outv)[i] = __float2bfloat16(v);
}

// ---------------- host-side layer driver ----------------
template<bool XFOLLOW, int H, bool ELU>
static void run_layer(const void* x, const void* W,
                      const void* a_s, const void* a_d,
                      const void* b, const void* g, const void* be,
                      const int* rowStart, const unsigned short* srcL,
                      __hip_bfloat16* hB, float* alS, float* alD,
                      float* outF, const int* flag, hipStream_t stream)
{
  gemm_kernel<XFOLLOW><<<782, 256, 0, stream>>>(x, W, hB, flag);
  al_kernel<H><<<(NN*H + 255)/256, 256, 0, stream>>>(hB, a_s, a_d, alS, alD, flag);
  aggln_kernel<H, ELU><<<12500, 256, 0, stream>>>(rowStart, srcL, alS, alD, hB,
                                                  b, g, be, outF, flag);
}

extern "C" void kernel_launch(void* const* d_in, const int* in_sizes, int n_in,
                              void* d_out, int out_size, void* d_ws, size_t ws_size,
                              hipStream_t stream)
{
  // ws layout (~31.1 MB)
  char* w = (char*)d_ws;
  int*   flag     = (int*)w;                 w += 256;
  float* accF     = (float*)w;               w += (size_t)NN*DD*4;     // 25.6 MB
  float* alS      = (float*)w;               w += (size_t)NN*8*4;      // 1.6 MB
  float* alD      = (float*)w;               w += (size_t)NN*8*4;      // 1.6 MB
  int*   deg      = (int*)w;                 w += (size_t)NN*4;        // 200 KB
  int*   rowStart = (int*)w;                 w += (size_t)(NN+1)*4;    // 200 KB
  int*   cursor   = (int*)w;                 w += (size_t)NN*4;        // 200 KB
  unsigned short* srcL = (unsigned short*)w; w += (size_t)EP*2;        // 1.7 MB
  if (ws_size < (size_t)(w - (char*)d_ws)) return;

  const void* x  = d_in[0];
  const int*  ei = (const int*)d_in[1];
  const void *W0=d_in[2], *as0=d_in[3], *ad0=d_in[4], *b0=d_in[5], *g0=d_in[6], *be0=d_in[7];
  const void *W1=d_in[8], *as1=d_in[9], *ad1=d_in[10],*b1=d_in[11],*g1=d_in[12],*be1=d_in[13];
  const void *W2=d_in[14],*as2=d_in[15],*ad2=d_in[16],*b2=d_in[17],*g2=d_in[18],*be2=d_in[19];

  __hip_bfloat16* hB = (__hip_bfloat16*)d_out;   // h staged in d_out (bf16, 12.8 MB)

  probe_kernel<<<1, 256, 0, stream>>>((const unsigned short*)x, flag);

  // CSR build (per launch; edge_index is restored before every call)
  zero_deg_kernel<<<(NN + 255)/256, 256, 0, stream>>>(deg);
  hist_kernel<<<(EP + 255)/256, 256, 0, stream>>>(ei, deg);
  scan_kernel<<<1, 1024, 0, stream>>>(deg, rowStart, cursor);
  scatter_kernel<<<(EP + 255)/256, 256, 0, stream>>>(ei, cursor, srcL);

  // layer 0: x = probed dtype, 8 heads, ELU
  run_layer<true, 8, true>(x,    W0, as0, ad0, b0, g0, be0,
                           rowStart, srcL, hB, alS, alD, accF, flag, stream);
  // layer 1: x = accF (f32), 8 heads, ELU
  run_layer<false, 8, true>(accF, W1, as1, ad1, b1, g1, be1,
                           rowStart, srcL, hB, alS, alD, accF, flag, stream);
  // layer 2: x = accF (f32), 1 head, plain LN
  run_layer<false, 1, false>(accF, W2, as2, ad2, b2, g2, be2,
                           rowStart, srcL, hB, alS, alD, accF, flag, stream);
  conv_kernel<<<25000, 256, 0, stream>>>(accF, d_out, flag);
}

// Round 5
// 607.260 us; speedup vs baseline: 5.3646x; 2.1978x over previous
//
#include <hip/hip_runtime.h>
#include <hip/hip_bf16.h>

#define NN 50000
#define EE 800000
#define EP 850000   // EE + NN self-loops
#define DD 128
#define NB 196      // ceil(NN/256)

__device__ __forceinline__ float bf2f(__hip_bfloat16 x){ return __bfloat162float(x); }
__device__ __forceinline__ float bfu(unsigned short u){ return __uint_as_float(((unsigned)u)<<16); }
// load float tensor element i, dtype selected at runtime (f32 ? float : bf16)
__device__ __forceinline__ float ldf(const void* p, size_t i, int f32){
  return f32 ? ((const float*)p)[i] : bf2f(((const __hip_bfloat16*)p)[i]);
}

// ---------------- dtype probe: f32 storage read as bf16 shows NaN/Inf exponents ----------------
__global__ void probe_kernel(const unsigned short* __restrict__ xu, int* __restrict__ flag)
{
  __shared__ int sc[256];
  int c = 0;
  for (int i = threadIdx.x; i < 32768; i += 256)
    if ((xu[i] & 0x7F80) == 0x7F80) c++;
  sc[threadIdx.x] = c;
  __syncthreads();
  for (int s = 128; s > 0; s >>= 1){
    if (threadIdx.x < s) sc[threadIdx.x] += sc[threadIdx.x + s];
    __syncthreads();
  }
  if (threadIdx.x == 0) flag[0] = (sc[0] > 16) ? 1 : 0;   // 1 => tensors are float32
}

// ---------------- CSR build ----------------
__global__ void __launch_bounds__(256) zero_deg_kernel(int* __restrict__ deg)
{
  int i = blockIdx.x*256 + threadIdx.x;
  if (i < NN) deg[i] = 0;
}

__global__ void __launch_bounds__(256) hist_kernel(const int* __restrict__ ei, int* __restrict__ deg)
{
  int e = blockIdx.x*256 + threadIdx.x;
  if (e >= EP) return;
  int d = (e < EE) ? ei[EE + e] : e - EE;
  atomicAdd(&deg[d], 1);
}

// two-level exclusive scan: (1) per-block scan, (2) scan of block sums, (3) add offsets
__global__ void __launch_bounds__(256) scan1_kernel(const int* __restrict__ deg,
    int* __restrict__ rowStart, int* __restrict__ blockSums)
{
  __shared__ int buf[256];
  int i = blockIdx.x*256 + threadIdx.x;
  int v = (i < NN) ? deg[i] : 0;
  buf[threadIdx.x] = v;
  __syncthreads();
  for (int off = 1; off < 256; off <<= 1){
    int t = (threadIdx.x >= off) ? buf[threadIdx.x - off] : 0;
    __syncthreads();
    buf[threadIdx.x] += t;
    __syncthreads();
  }
  if (i < NN) rowStart[i] = buf[threadIdx.x] - v;   // local exclusive
  if (threadIdx.x == 255) blockSums[blockIdx.x] = buf[255];
}

__global__ void __launch_bounds__(256) scan2_kernel(int* __restrict__ blockSums)
{
  __shared__ int buf[256];
  int v = (threadIdx.x < NB) ? blockSums[threadIdx.x] : 0;
  buf[threadIdx.x] = v;
  __syncthreads();
  for (int off = 1; off < 256; off <<= 1){
    int t = (threadIdx.x >= off) ? buf[threadIdx.x - off] : 0;
    __syncthreads();
    buf[threadIdx.x] += t;
    __syncthreads();
  }
  if (threadIdx.x < NB) blockSums[threadIdx.x] = buf[threadIdx.x] - v;  // exclusive
}

__global__ void __launch_bounds__(256) scan3_kernel(int* __restrict__ rowStart,
    const int* __restrict__ blockSums, int* __restrict__ cursor)
{
  int i = blockIdx.x*256 + threadIdx.x;
  if (i < NN){
    int v = rowStart[i] + blockSums[blockIdx.x];
    rowStart[i] = v;
    cursor[i]   = v;
  }
  if (i == 0) rowStart[NN] = EP;
}

__global__ void __launch_bounds__(256) scatter_kernel(const int* __restrict__ ei,
    int* __restrict__ cursor, unsigned short* __restrict__ srcL)
{
  int e = blockIdx.x*256 + threadIdx.x;
  if (e >= EP) return;
  int s, d;
  if (e < EE){ s = ei[e]; d = ei[EE + e]; } else { s = d = e - EE; }
  int pos = atomicAdd(&cursor[d], 1);
  srcL[pos] = (unsigned short)s;
}

// ---------------- GEMM: Hout[n][c] = sum_k X[n][k]*W[k][c], bf16 out ----------------
__device__ __forceinline__ void fma_step(float w0, float w1, float w2, float w3,
                                         const float* __restrict__ xr, float acc[8][4])
{
  const float4 xa = *(const float4*)xr;
  const float4 xb = *(const float4*)(xr + 4);
  acc[0][0] += xa.x*w0; acc[0][1] += xa.x*w1; acc[0][2] += xa.x*w2; acc[0][3] += xa.x*w3;
  acc[1][0] += xa.y*w0; acc[1][1] += xa.y*w1; acc[1][2] += xa.y*w2; acc[1][3] += xa.y*w3;
  acc[2][0] += xa.z*w0; acc[2][1] += xa.z*w1; acc[2][2] += xa.z*w2; acc[2][3] += xa.z*w3;
  acc[3][0] += xa.w*w0; acc[3][1] += xa.w*w1; acc[3][2] += xa.w*w2; acc[3][3] += xa.w*w3;
  acc[4][0] += xb.x*w0; acc[4][1] += xb.x*w1; acc[4][2] += xb.x*w2; acc[4][3] += xb.x*w3;
  acc[5][0] += xb.y*w0; acc[5][1] += xb.y*w1; acc[5][2] += xb.y*w2; acc[5][3] += xb.y*w3;
  acc[6][0] += xb.z*w0; acc[6][1] += xb.z*w1; acc[6][2] += xb.z*w2; acc[6][3] += xb.z*w3;
  acc[7][0] += xb.w*w0; acc[7][1] += xb.w*w1; acc[7][2] += xb.w*w2; acc[7][3] += xb.w*w3;
}

template<bool XFOLLOW>
__global__ void __launch_bounds__(256) gemm_kernel(const void* __restrict__ Xv,
                                                   const void* __restrict__ Wv,
                                                   __hip_bfloat16* __restrict__ Hout,
                                                   const int* __restrict__ flag)
{
  const int f  = flag[0];
  const int xf = XFOLLOW ? f : 1;
  __shared__ float xs[128][68];
  const int tid  = threadIdx.x;
  const int row0 = blockIdx.x * 64;
  #pragma unroll
  for (int i = 0; i < 32; i++){
    int idx = tid + i*256;
    int r = idx >> 7, k = idx & 127;
    int row = row0 + r;
    xs[k][r] = (row < NN) ? ldf(Xv, (size_t)row*DD + k, xf) : 0.f;
  }
  __syncthreads();

  const int cg = tid & 31, rg = tid >> 5;
  const int c0 = cg*4,    r0 = rg*8;
  float acc[8][4];
  #pragma unroll
  for (int i=0;i<8;i++){ acc[i][0]=0.f; acc[i][1]=0.f; acc[i][2]=0.f; acc[i][3]=0.f; }

  if (f){
    const float* Wf = (const float*)Wv;
    #pragma unroll 4
    for (int k = 0; k < 128; k++){
      float4 wv = *(const float4*)(Wf + (size_t)k*DD + c0);
      fma_step(wv.x, wv.y, wv.z, wv.w, &xs[k][r0], acc);
    }
  } else {
    const __hip_bfloat16* Wb = (const __hip_bfloat16*)Wv;
    #pragma unroll 4
    for (int k = 0; k < 128; k++){
      uint2 wv = *(const uint2*)(Wb + (size_t)k*DD + c0);
      fma_step(__uint_as_float(wv.x << 16), __uint_as_float(wv.x & 0xffff0000u),
               __uint_as_float(wv.y << 16), __uint_as_float(wv.y & 0xffff0000u),
               &xs[k][r0], acc);
    }
  }
  #pragma unroll
  for (int i = 0; i < 8; i++){
    int row = row0 + r0 + i;
    if (row < NN){
      __hip_bfloat16 o[4];
      o[0] = __float2bfloat16(acc[i][0]);
      o[1] = __float2bfloat16(acc[i][1]);
      o[2] = __float2bfloat16(acc[i][2]);
      o[3] = __float2bfloat16(acc[i][3]);
      *(uint2*)&Hout[(size_t)row*DD + c0] = *(const uint2*)o;
    }
  }
}

// ---------------- per-(node,head) attention scalars ----------------
template<int H>
__global__ void __launch_bounds__(256) al_kernel(const __hip_bfloat16* __restrict__ hB,
    const void* __restrict__ a_s, const void* __restrict__ a_d,
    float* __restrict__ alS, float* __restrict__ alD, const int* __restrict__ flag)
{
  const int f = flag[0];
  const int C = DD / H;
  int gid = blockIdx.x*256 + threadIdx.x;
  if (gid >= NN*H) return;
  int n = gid / H, hd = gid % H;
  float ps = 0.f, pd = 0.f;
  #pragma unroll
  for (int c = 0; c < C; c++){
    float hv = bf2f(hB[(size_t)n*DD + hd*C + c]);
    ps += hv * ldf(a_s, hd*C + c, f);
    pd += hv * ldf(a_d, hd*C + c, f);
  }
  alS[gid] = ps;
  alD[gid] = pd;
}

// ---------------- fused: per-dst softmax + gather-aggregate + bias + LN (+ELU) ----------------
// Single pass: softmax is shift-invariant and logits are O(1) here, so no max pass.
// one wave per dst node; lane covers channels 2*lane, 2*lane+1
template<int H, bool ELU>
__global__ void __launch_bounds__(256) aggln_kernel(
    const int* __restrict__ rowStart, const unsigned short* __restrict__ srcL,
    const float* __restrict__ alS, const float* __restrict__ alD,
    const __hip_bfloat16* __restrict__ hB,
    const void* __restrict__ b, const void* __restrict__ g, const void* __restrict__ be,
    float* __restrict__ outF, const int* __restrict__ flag)
{
  const int f    = flag[0];
  const int lane = threadIdx.x & 63;
  const int d    = blockIdx.x*4 + (threadIdx.x >> 6);
  const int C    = DD / H;
  const int c0   = lane*2;
  const int hd   = c0 / C;
  const int start = rowStart[d], end = rowStart[d+1];
  const float aldv = alD[d*H + hd];

  float ssum = 0.f, a0 = 0.f, a1 = 0.f;
  int sNext = srcL[start];                 // deg >= 1 (self-loop)
  for (int i = start; i < end; i++){
    int s = sNext;
    if (i + 1 < end) sNext = srcL[i+1];    // one-ahead prefetch
    float el = alS[s*H + hd] + aldv;
    el = el > 0.f ? el : 0.2f*el;
    el = fminf(el, 80.f);                  // exp overflow guard (never hit in practice)
    float w = __expf(el);
    ushort2 hv = *(const ushort2*)&hB[(size_t)s*DD + c0];
    ssum += w;
    a0 = fmaf(bfu(hv.x), w, a0);
    a1 = fmaf(bfu(hv.y), w, a1);
  }
  const float sinv = 1.f / ssum;

  // bias + LayerNorm across the wave's 128 channels
  float v0 = a0*sinv + ldf(b, c0, f), v1 = a1*sinv + ldf(b, c0+1, f);
  float s2 = v0 + v1;
  #pragma unroll
  for (int off = 32; off >= 1; off >>= 1) s2 += __shfl_xor(s2, off, 64);
  float mu = s2 * (1.0f/128.0f);
  float d0 = v0 - mu, d1 = v1 - mu;
  float q = d0*d0 + d1*d1;
  #pragma unroll
  for (int off = 32; off >= 1; off >>= 1) q += __shfl_xor(q, off, 64);
  float r = rsqrtf(q*(1.0f/128.0f) + 1e-5f);
  float y0 = d0*r*ldf(g, c0, f)   + ldf(be, c0, f);
  float y1 = d1*r*ldf(g, c0+1, f) + ldf(be, c0+1, f);
  if (ELU){
    y0 = y0 > 0.f ? y0 : __expf(y0) - 1.f;
    y1 = y1 > 0.f ? y1 : __expf(y1) - 1.f;
  }
  *(float2*)&outF[(size_t)d*DD + c0] = make_float2(y0, y1);
}

// ---------------- final convert accF -> d_out (dtype per flag) ----------------
__global__ void __launch_bounds__(256) conv_kernel(const float* __restrict__ acc,
    void* __restrict__ outv, const int* __restrict__ flag)
{
  int i = blockIdx.x*256 + threadIdx.x;   // grid covers NN*DD exactly
  float v = acc[i];
  if (flag[0]) ((float*)outv)[i] = v;
  else ((__hip_bfloat16*)outv)[i] = __float2bfloat16(v);
}

// ---------------- host-side layer driver ----------------
template<bool XFOLLOW, int H, bool ELU>
static void run_layer(const void* x, const void* W,
                      const void* a_s, const void* a_d,
                      const void* b, const void* g, const void* be,
                      const int* rowStart, const unsigned short* srcL,
                      __hip_bfloat16* hB, float* alS, float* alD,
                      float* outF, const int* flag, hipStream_t stream)
{
  gemm_kernel<XFOLLOW><<<782, 256, 0, stream>>>(x, W, hB, flag);
  al_kernel<H><<<(NN*H + 255)/256, 256, 0, stream>>>(hB, a_s, a_d, alS, alD, flag);
  aggln_kernel<H, ELU><<<12500, 256, 0, stream>>>(rowStart, srcL, alS, alD, hB,
                                                  b, g, be, outF, flag);
}

extern "C" void kernel_launch(void* const* d_in, const int* in_sizes, int n_in,
                              void* d_out, int out_size, void* d_ws, size_t ws_size,
                              hipStream_t stream)
{
  // ws layout (~31.3 MB)
  char* w = (char*)d_ws;
  int*   flag     = (int*)w;                 w += 256;
  float* accF     = (float*)w;               w += (size_t)NN*DD*4;     // 25.6 MB
  float* alS      = (float*)w;               w += (size_t)NN*8*4;      // 1.6 MB
  float* alD      = (float*)w;               w += (size_t)NN*8*4;      // 1.6 MB
  int*   deg      = (int*)w;                 w += (size_t)NN*4;        // 200 KB
  int*   rowStart = (int*)w;                 w += (size_t)(NN+1)*4;    // 200 KB
  int*   cursor   = (int*)w;                 w += (size_t)NN*4;        // 200 KB
  int*   blockSums= (int*)w;                 w += 1024;                // NB ints
  unsigned short* srcL = (unsigned short*)w; w += (size_t)EP*2;        // 1.7 MB
  if (ws_size < (size_t)(w - (char*)d_ws)) return;

  const void* x  = d_in[0];
  const int*  ei = (const int*)d_in[1];
  const void *W0=d_in[2], *as0=d_in[3], *ad0=d_in[4], *b0=d_in[5], *g0=d_in[6], *be0=d_in[7];
  const void *W1=d_in[8], *as1=d_in[9], *ad1=d_in[10],*b1=d_in[11],*g1=d_in[12],*be1=d_in[13];
  const void *W2=d_in[14],*as2=d_in[15],*ad2=d_in[16],*b2=d_in[17],*g2=d_in[18],*be2=d_in[19];

  __hip_bfloat16* hB = (__hip_bfloat16*)d_out;   // h staged in d_out (bf16, 12.8 MB)

  probe_kernel<<<1, 256, 0, stream>>>((const unsigned short*)x, flag);

  // CSR build (per launch; edge_index is restored before every call)
  zero_deg_kernel<<<NB, 256, 0, stream>>>(deg);
  hist_kernel<<<(EP + 255)/256, 256, 0, stream>>>(ei, deg);
  scan1_kernel<<<NB, 256, 0, stream>>>(deg, rowStart, blockSums);
  scan2_kernel<<<1, 256, 0, stream>>>(blockSums);
  scan3_kernel<<<NB, 256, 0, stream>>>(rowStart, blockSums, cursor);
  scatter_kernel<<<(EP + 255)/256, 256, 0, stream>>>(ei, cursor, srcL);

  // layer 0: x = probed dtype, 8 heads, ELU
  run_layer<true, 8, true>(x,    W0, as0, ad0, b0, g0, be0,
                           rowStart, srcL, hB, alS, alD, accF, flag, stream);
  // layer 1: x = accF (f32), 8 heads, ELU
  run_layer<false, 8, true>(accF, W1, as1, ad1, b1, g1, be1,
                           rowStart, srcL, hB, alS, alD, accF, flag, stream);
  // layer 2: x = accF (f32), 1 head, plain LN
  run_layer<false, 1, false>(accF, W2, as2, ad2, b2, g2, be2,
                           rowStart, srcL, hB, alS, alD, accF, flag, stream);
  conv_kernel<<<25000, 256, 0, stream>>>(accF, d_out, flag);
}

// Round 6
// 480.647 us; speedup vs baseline: 6.7777x; 1.2634x over previous
//
#include <hip/hip_runtime.h>
#include <hip/hip_bf16.h>

#define NN 50000
#define EE 800000
#define EP 850000   // EE + NN self-loops
#define DD 128
#define NB 196      // ceil(NN/256)

__device__ __forceinline__ float bf2f(__hip_bfloat16 x){ return __bfloat162float(x); }
__device__ __forceinline__ float bfu(unsigned short u){ return __uint_as_float(((unsigned)u)<<16); }
// load float tensor element i, dtype selected at runtime (f32 ? float : bf16)
__device__ __forceinline__ float ldf(const void* p, size_t i, int f32){
  return f32 ? ((const float*)p)[i] : bf2f(((const __hip_bfloat16*)p)[i]);
}

// ---------------- probe dtype (block 0) + zero deg (all blocks) ----------------
__global__ void __launch_bounds__(256) probe_zero_kernel(const unsigned short* __restrict__ xu,
    int* __restrict__ flag, int* __restrict__ deg)
{
  int i = blockIdx.x*256 + threadIdx.x;
  if (i < NN) deg[i] = 0;
  if (blockIdx.x == 0){
    __shared__ int sc[256];
    int c = 0;
    for (int k = threadIdx.x; k < 32768; k += 256)
      if ((xu[k] & 0x7F80) == 0x7F80) c++;        // bf16 inf/nan exponent pattern
    sc[threadIdx.x] = c;
    __syncthreads();
    for (int s = 128; s > 0; s >>= 1){
      if (threadIdx.x < s) sc[threadIdx.x] += sc[threadIdx.x + s];
      __syncthreads();
    }
    if (threadIdx.x == 0) flag[0] = (sc[0] > 16) ? 1 : 0;   // 1 => tensors are float32
  }
}

// ---------------- CSR build ----------------
__global__ void __launch_bounds__(256) hist_kernel(const int* __restrict__ ei, int* __restrict__ deg)
{
  int e = blockIdx.x*256 + threadIdx.x;
  if (e >= EP) return;
  int d = (e < EE) ? ei[EE + e] : e - EE;
  atomicAdd(&deg[d], 1);
}

// two-level exclusive scan
__global__ void __launch_bounds__(256) scan1_kernel(const int* __restrict__ deg,
    int* __restrict__ rowStart, int* __restrict__ blockSums)
{
  __shared__ int buf[256];
  int i = blockIdx.x*256 + threadIdx.x;
  int v = (i < NN) ? deg[i] : 0;
  buf[threadIdx.x] = v;
  __syncthreads();
  for (int off = 1; off < 256; off <<= 1){
    int t = (threadIdx.x >= off) ? buf[threadIdx.x - off] : 0;
    __syncthreads();
    buf[threadIdx.x] += t;
    __syncthreads();
  }
  if (i < NN) rowStart[i] = buf[threadIdx.x] - v;
  if (threadIdx.x == 255) blockSums[blockIdx.x] = buf[255];
}

__global__ void __launch_bounds__(256) scan2_kernel(int* __restrict__ blockSums)
{
  __shared__ int buf[256];
  int v = (threadIdx.x < NB) ? blockSums[threadIdx.x] : 0;
  buf[threadIdx.x] = v;
  __syncthreads();
  for (int off = 1; off < 256; off <<= 1){
    int t = (threadIdx.x >= off) ? buf[threadIdx.x - off] : 0;
    __syncthreads();
    buf[threadIdx.x] += t;
    __syncthreads();
  }
  if (threadIdx.x < NB) blockSums[threadIdx.x] = buf[threadIdx.x] - v;
}

__global__ void __launch_bounds__(256) scan3_kernel(int* __restrict__ rowStart,
    const int* __restrict__ blockSums, int* __restrict__ cursor)
{
  int i = blockIdx.x*256 + threadIdx.x;
  if (i < NN){
    int v = rowStart[i] + blockSums[blockIdx.x];
    rowStart[i] = v;
    cursor[i]   = v;
  }
  if (i == 0) rowStart[NN] = EP;
}

__global__ void __launch_bounds__(256) scatter_kernel(const int* __restrict__ ei,
    int* __restrict__ cursor, unsigned short* __restrict__ srcL)
{
  int e = blockIdx.x*256 + threadIdx.x;
  if (e >= EP) return;
  int s, d;
  if (e < EE){ s = ei[e]; d = ei[EE + e]; } else { s = d = e - EE; }
  int pos = atomicAdd(&cursor[d], 1);
  srcL[pos] = (unsigned short)s;
}

// ---------------- GEMM + fused al epilogue ----------------
__device__ __forceinline__ void fma_step(float w0, float w1, float w2, float w3,
                                         const float* __restrict__ xr, float acc[8][4])
{
  const float4 xa = *(const float4*)xr;
  const float4 xb = *(const float4*)(xr + 4);
  acc[0][0] += xa.x*w0; acc[0][1] += xa.x*w1; acc[0][2] += xa.x*w2; acc[0][3] += xa.x*w3;
  acc[1][0] += xa.y*w0; acc[1][1] += xa.y*w1; acc[1][2] += xa.y*w2; acc[1][3] += xa.y*w3;
  acc[2][0] += xa.z*w0; acc[2][1] += xa.z*w1; acc[2][2] += xa.z*w2; acc[2][3] += xa.z*w3;
  acc[3][0] += xa.w*w0; acc[3][1] += xa.w*w1; acc[3][2] += xa.w*w2; acc[3][3] += xa.w*w3;
  acc[4][0] += xb.x*w0; acc[4][1] += xb.x*w1; acc[4][2] += xb.x*w2; acc[4][3] += xb.x*w3;
  acc[5][0] += xb.y*w0; acc[5][1] += xb.y*w1; acc[5][2] += xb.y*w2; acc[5][3] += xb.y*w3;
  acc[6][0] += xb.z*w0; acc[6][1] += xb.z*w1; acc[6][2] += xb.z*w2; acc[6][3] += xb.z*w3;
  acc[7][0] += xb.w*w0; acc[7][1] += xb.w*w1; acc[7][2] += xb.w*w2; acc[7][3] += xb.w*w3;
}

template<bool XFOLLOW, int H>
__global__ void __launch_bounds__(256) gemm_kernel(const void* __restrict__ Xv,
                                                   const void* __restrict__ Wv,
                                                   const void* __restrict__ a_s,
                                                   const void* __restrict__ a_d,
                                                   __hip_bfloat16* __restrict__ Hout,
                                                   float* __restrict__ alS,
                                                   float* __restrict__ alD,
                                                   const int* __restrict__ flag)
{
  const int f  = flag[0];
  const int xf = XFOLLOW ? f : 1;
  __shared__ float xs[128][68];
  const int tid  = threadIdx.x;
  const int row0 = blockIdx.x * 64;
  #pragma unroll
  for (int i = 0; i < 32; i++){
    int idx = tid + i*256;
    int r = idx >> 7, k = idx & 127;
    int row = row0 + r;
    xs[k][r] = (row < NN) ? ldf(Xv, (size_t)row*DD + k, xf) : 0.f;
  }
  __syncthreads();

  const int cg = tid & 31, rg = tid >> 5;
  const int c0 = cg*4,    r0 = rg*8;
  float acc[8][4];
  #pragma unroll
  for (int i=0;i<8;i++){ acc[i][0]=0.f; acc[i][1]=0.f; acc[i][2]=0.f; acc[i][3]=0.f; }

  if (f){
    const float* Wf = (const float*)Wv;
    #pragma unroll 4
    for (int k = 0; k < 128; k++){
      float4 wv = *(const float4*)(Wf + (size_t)k*DD + c0);
      fma_step(wv.x, wv.y, wv.z, wv.w, &xs[k][r0], acc);
    }
  } else {
    const __hip_bfloat16* Wb = (const __hip_bfloat16*)Wv;
    #pragma unroll 4
    for (int k = 0; k < 128; k++){
      uint2 wv = *(const uint2*)(Wb + (size_t)k*DD + c0);
      fma_step(__uint_as_float(wv.x << 16), __uint_as_float(wv.x & 0xffff0000u),
               __uint_as_float(wv.y << 16), __uint_as_float(wv.y & 0xffff0000u),
               &xs[k][r0], acc);
    }
  }

  // store h (bf16)
  #pragma unroll
  for (int i = 0; i < 8; i++){
    int row = row0 + r0 + i;
    if (row < NN){
      __hip_bfloat16 o[4];
      o[0] = __float2bfloat16(acc[i][0]);
      o[1] = __float2bfloat16(acc[i][1]);
      o[2] = __float2bfloat16(acc[i][2]);
      o[3] = __float2bfloat16(acc[i][3]);
      *(uint2*)&Hout[(size_t)row*DD + c0] = *(const uint2*)o;
    }
  }

  // fused al: per-(row,head) dots with a_src/a_dst, reduced across the cg group
  float asv0 = ldf(a_s, c0+0, f), asv1 = ldf(a_s, c0+1, f);
  float asv2 = ldf(a_s, c0+2, f), asv3 = ldf(a_s, c0+3, f);
  float adv0 = ldf(a_d, c0+0, f), adv1 = ldf(a_d, c0+1, f);
  float adv2 = ldf(a_d, c0+2, f), adv3 = ldf(a_d, c0+3, f);
  float ps[8], pd[8];
  #pragma unroll
  for (int i = 0; i < 8; i++){
    ps[i] = acc[i][0]*asv0 + acc[i][1]*asv1 + acc[i][2]*asv2 + acc[i][3]*asv3;
    pd[i] = acc[i][0]*adv0 + acc[i][1]*adv1 + acc[i][2]*adv2 + acc[i][3]*adv3;
  }
  const int REDW = (H == 8) ? 2 : 16;     // reduce across 4 lanes (16ch head) or 32 lanes (128ch)
  #pragma unroll
  for (int off = 1; off <= REDW; off <<= 1){
    #pragma unroll
    for (int i = 0; i < 8; i++){
      ps[i] += __shfl_xor(ps[i], off, 64);
      pd[i] += __shfl_xor(pd[i], off, 64);
    }
  }
  if (H == 8){
    if ((cg & 3) == 0){
      int hd = cg >> 2;
      #pragma unroll
      for (int i = 0; i < 8; i++){
        int row = row0 + r0 + i;
        if (row < NN){ alS[row*8 + hd] = ps[i]; alD[row*8 + hd] = pd[i]; }
      }
    }
  } else {
    if (cg == 0){
      #pragma unroll
      for (int i = 0; i < 8; i++){
        int row = row0 + r0 + i;
        if (row < NN){ alS[row] = ps[i]; alD[row] = pd[i]; }
      }
    }
  }
}

// ---------------- fused: per-dst softmax + gather-aggregate + bias + LN (+ELU) ----------------
// one wave per dst node; lane covers channels 2*lane, 2*lane+1.
// Edge ids broadcast from registers via shuffle (lane L holds srcL[base+L]).
template<int H, bool ELU>
__global__ void __launch_bounds__(256) aggln_kernel(
    const int* __restrict__ rowStart, const unsigned short* __restrict__ srcL,
    const float* __restrict__ alS, const float* __restrict__ alD,
    const __hip_bfloat16* __restrict__ hB,
    const void* __restrict__ b, const void* __restrict__ g, const void* __restrict__ be,
    float* __restrict__ outF, const int* __restrict__ flag)
{
  const int f    = flag[0];
  const int lane = threadIdx.x & 63;
  const int d    = blockIdx.x*4 + (threadIdx.x >> 6);
  const int C    = DD / H;
  const int c0   = lane*2;
  const int hd   = c0 / C;
  const int start = rowStart[d], end = rowStart[d+1];
  const float aldv = alD[d*H + hd];

  float ssum = 0.f, a0 = 0.f, a1 = 0.f;
  for (int base = start; base < end; base += 64){
    int cnt = min(64, end - base);
    int myS = (base + lane < end) ? (int)srcL[base + lane] : 0;
    int j = 0;
    for (; j + 1 < cnt; j += 2){
      int s0 = __shfl(myS, j, 64);
      int s1 = __shfl(myS, j+1, 64);
      float el0 = alS[s0*H + hd] + aldv;
      float el1 = alS[s1*H + hd] + aldv;
      el0 = el0 > 0.f ? el0 : 0.2f*el0;
      el1 = el1 > 0.f ? el1 : 0.2f*el1;
      float w0 = __expf(fminf(el0, 80.f));
      float w1 = __expf(fminf(el1, 80.f));
      ushort2 h0 = *(const ushort2*)&hB[(size_t)s0*DD + c0];
      ushort2 h1 = *(const ushort2*)&hB[(size_t)s1*DD + c0];
      ssum += w0 + w1;
      a0 = fmaf(bfu(h0.x), w0, a0);
      a1 = fmaf(bfu(h0.y), w0, a1);
      a0 = fmaf(bfu(h1.x), w1, a0);
      a1 = fmaf(bfu(h1.y), w1, a1);
    }
    if (j < cnt){
      int s0 = __shfl(myS, j, 64);
      float el0 = alS[s0*H + hd] + aldv;
      el0 = el0 > 0.f ? el0 : 0.2f*el0;
      float w0 = __expf(fminf(el0, 80.f));
      ushort2 h0 = *(const ushort2*)&hB[(size_t)s0*DD + c0];
      ssum += w0;
      a0 = fmaf(bfu(h0.x), w0, a0);
      a1 = fmaf(bfu(h0.y), w0, a1);
    }
  }
  const float sinv = 1.f / ssum;

  // bias + LayerNorm across the wave's 128 channels
  float v0 = a0*sinv + ldf(b, c0, f), v1 = a1*sinv + ldf(b, c0+1, f);
  float s2 = v0 + v1;
  #pragma unroll
  for (int off = 32; off >= 1; off >>= 1) s2 += __shfl_xor(s2, off, 64);
  float mu = s2 * (1.0f/128.0f);
  float d0 = v0 - mu, d1 = v1 - mu;
  float q = d0*d0 + d1*d1;
  #pragma unroll
  for (int off = 32; off >= 1; off >>= 1) q += __shfl_xor(q, off, 64);
  float r = rsqrtf(q*(1.0f/128.0f) + 1e-5f);
  float y0 = d0*r*ldf(g, c0, f)   + ldf(be, c0, f);
  float y1 = d1*r*ldf(g, c0+1, f) + ldf(be, c0+1, f);
  if (ELU){
    y0 = y0 > 0.f ? y0 : __expf(y0) - 1.f;
    y1 = y1 > 0.f ? y1 : __expf(y1) - 1.f;
  }
  *(float2*)&outF[(size_t)d*DD + c0] = make_float2(y0, y1);
}

// ---------------- final convert accF -> d_out (dtype per flag) ----------------
__global__ void __launch_bounds__(256) conv_kernel(const float* __restrict__ acc,
    void* __restrict__ outv, const int* __restrict__ flag)
{
  int i = blockIdx.x*256 + threadIdx.x;   // grid covers NN*DD exactly
  float v = acc[i];
  if (flag[0]) ((float*)outv)[i] = v;
  else ((__hip_bfloat16*)outv)[i] = __float2bfloat16(v);
}

// ---------------- host-side layer driver ----------------
template<bool XFOLLOW, int H, bool ELU>
static void run_layer(const void* x, const void* W,
                      const void* a_s, const void* a_d,
                      const void* b, const void* g, const void* be,
                      const int* rowStart, const unsigned short* srcL,
                      __hip_bfloat16* hB, float* alS, float* alD,
                      float* outF, const int* flag, hipStream_t stream)
{
  gemm_kernel<XFOLLOW, H><<<782, 256, 0, stream>>>(x, W, a_s, a_d, hB, alS, alD, flag);
  aggln_kernel<H, ELU><<<12500, 256, 0, stream>>>(rowStart, srcL, alS, alD, hB,
                                                  b, g, be, outF, flag);
}

extern "C" void kernel_launch(void* const* d_in, const int* in_sizes, int n_in,
                              void* d_out, int out_size, void* d_ws, size_t ws_size,
                              hipStream_t stream)
{
  // ws layout (~31.3 MB)
  char* w = (char*)d_ws;
  int*   flag     = (int*)w;                 w += 256;
  float* accF     = (float*)w;               w += (size_t)NN*DD*4;     // 25.6 MB
  float* alS      = (float*)w;               w += (size_t)NN*8*4;      // 1.6 MB
  float* alD      = (float*)w;               w += (size_t)NN*8*4;      // 1.6 MB
  int*   deg      = (int*)w;                 w += (size_t)NN*4;        // 200 KB
  int*   rowStart = (int*)w;                 w += (size_t)(NN+1)*4;    // 200 KB
  int*   cursor   = (int*)w;                 w += (size_t)NN*4;        // 200 KB
  int*   blockSums= (int*)w;                 w += 1024;                // NB ints
  unsigned short* srcL = (unsigned short*)w; w += (size_t)EP*2;        // 1.7 MB
  if (ws_size < (size_t)(w - (char*)d_ws)) return;

  const void* x  = d_in[0];
  const int*  ei = (const int*)d_in[1];
  const void *W0=d_in[2], *as0=d_in[3], *ad0=d_in[4], *b0=d_in[5], *g0=d_in[6], *be0=d_in[7];
  const void *W1=d_in[8], *as1=d_in[9], *ad1=d_in[10],*b1=d_in[11],*g1=d_in[12],*be1=d_in[13];
  const void *W2=d_in[14],*as2=d_in[15],*ad2=d_in[16],*b2=d_in[17],*g2=d_in[18],*be2=d_in[19];

  __hip_bfloat16* hB = (__hip_bfloat16*)d_out;   // h staged in d_out (bf16, 12.8 MB)

  // CSR build (per launch; edge_index is restored before every call)
  probe_zero_kernel<<<NB, 256, 0, stream>>>((const unsigned short*)x, flag, deg);
  hist_kernel<<<(EP + 255)/256, 256, 0, stream>>>(ei, deg);
  scan1_kernel<<<NB, 256, 0, stream>>>(deg, rowStart, blockSums);
  scan2_kernel<<<1, 256, 0, stream>>>(blockSums);
  scan3_kernel<<<NB, 256, 0, stream>>>(rowStart, blockSums, cursor);
  scatter_kernel<<<(EP + 255)/256, 256, 0, stream>>>(ei, cursor, srcL);

  // layer 0: x = probed dtype, 8 heads, ELU
  run_layer<true, 8, true>(x,    W0, as0, ad0, b0, g0, be0,
                           rowStart, srcL, hB, alS, alD, accF, flag, stream);
  // layer 1: x = accF (f32), 8 heads, ELU
  run_layer<false, 8, true>(accF, W1, as1, ad1, b1, g1, be1,
                           rowStart, srcL, hB, alS, alD, accF, flag, stream);
  // layer 2: x = accF (f32), 1 head, plain LN
  run_layer<false, 1, false>(accF, W2, as2, ad2, b2, g2, be2,
                           rowStart, srcL, hB, alS, alD, accF, flag, stream);
  conv_kernel<<<25000, 256, 0, stream>>>(accF, d_out, flag);
}

// Round 8
// 477.740 us; speedup vs baseline: 6.8190x; 1.0061x over previous
//
#include <hip/hip_runtime.h>
#include <hip/hip_bf16.h>

#define NN 50000
#define EE 800000
#define EP 850000   // EE + NN self-loops
#define DD 128
#define NB 196      // ceil(NN/256)

typedef __attribute__((ext_vector_type(8))) short short8;
typedef __attribute__((ext_vector_type(4))) float f32x4;

__device__ __forceinline__ float bf2f(__hip_bfloat16 x){ return __bfloat162float(x); }
__device__ __forceinline__ float bfu(unsigned short u){ return __uint_as_float(((unsigned)u)<<16); }
__device__ __forceinline__ unsigned short f2bs(float x){
  __hip_bfloat16 h = __float2bfloat16(x);
  union { __hip_bfloat16 h; unsigned short u; } cv; cv.h = h; return cv.u;
}
// load float tensor element i, dtype selected at runtime (f32 ? float : bf16)
__device__ __forceinline__ float ldf(const void* p, size_t i, int f32){
  return f32 ? ((const float*)p)[i] : bf2f(((const __hip_bfloat16*)p)[i]);
}

// ---------------- probe dtype (block 0) + zero deg (all blocks) ----------------
__global__ void __launch_bounds__(256) probe_zero_kernel(const unsigned short* __restrict__ xu,
    int* __restrict__ flag, int* __restrict__ deg)
{
  int i = blockIdx.x*256 + threadIdx.x;
  if (i < NN) deg[i] = 0;
  if (blockIdx.x == 0){
    __shared__ int sc[256];
    int c = 0;
    for (int k = threadIdx.x; k < 32768; k += 256)
      if ((xu[k] & 0x7F80) == 0x7F80) c++;        // bf16 inf/nan exponent pattern
    sc[threadIdx.x] = c;
    __syncthreads();
    for (int s = 128; s > 0; s >>= 1){
      if (threadIdx.x < s) sc[threadIdx.x] += sc[threadIdx.x + s];
      __syncthreads();
    }
    if (threadIdx.x == 0) flag[0] = (sc[0] > 16) ? 1 : 0;   // 1 => tensors are float32
  }
}

// ---------------- pack W (+ W@a_src, W@a_dst as tile 8) into MFMA B-fragment order ----------------
// Layout: Wmf[layer][t=c*4+kb][lane][j] = W[kb*32+(lane>>4)*8+j][c*16+(lane&15)]  (c<8)
// tile c==8: n=lane&15: n<8 -> (W@a_src)[k][head n], n>=8 -> (W@a_dst)[k][head n-8]
__global__ void __launch_bounds__(256) packw_kernel(
    const void* __restrict__ W0, const void* __restrict__ as0, const void* __restrict__ ad0,
    const void* __restrict__ W1, const void* __restrict__ as1, const void* __restrict__ ad1,
    const void* __restrict__ W2, const void* __restrict__ as2, const void* __restrict__ ad2,
    unsigned short* __restrict__ Wmf, const int* __restrict__ flag)
{
  const int f = flag[0];
  const int L = blockIdx.x / 9, seg = blockIdx.x % 9;
  const void *W, *as, *ad; int H;
  if (L == 0){ W = W0; as = as0; ad = ad0; H = 8; }
  else if (L == 1){ W = W1; as = as1; ad = ad1; H = 8; }
  else { W = W2; as = as2; ad = ad2; H = 1; }
  int idx = seg*256 + threadIdx.x;          // 0..2303
  int t = idx >> 6, lane = idx & 63;        // t 0..35
  int c = t >> 2, kb = t & 3;
  int m = lane & 15, quad = lane >> 4;
  unsigned short out[8];
  #pragma unroll
  for (int j = 0; j < 8; j++){
    int k = kb*32 + quad*8 + j;
    float v;
    if (c < 8){
      v = ldf(W, (size_t)k*DD + c*16 + m, f);
    } else {
      float s = 0.f;
      if (H == 8){
        int hd = m & 7;
        const void* av = (m < 8) ? as : ad;
        for (int i = 0; i < 16; i++)
          s += ldf(W, (size_t)k*DD + hd*16 + i, f) * ldf(av, hd*16 + i, f);
      } else {
        if (m < 2){
          const void* av = m ? ad : as;
          for (int i = 0; i < DD; i++)
            s += ldf(W, (size_t)k*DD + i, f) * ldf(av, i, f);
        }
      }
      v = s;
    }
    out[j] = f2bs(v);
  }
  *(uint4*)&Wmf[(((size_t)L*36 + t)*64 + lane)*8] = *(const uint4*)out;
}

// ---------------- CSR build ----------------
__global__ void __launch_bounds__(256) hist_kernel(const int* __restrict__ ei, int* __restrict__ deg)
{
  int e = blockIdx.x*256 + threadIdx.x;
  if (e >= EP) return;
  int d = (e < EE) ? ei[EE + e] : e - EE;
  atomicAdd(&deg[d], 1);
}

__global__ void __launch_bounds__(256) scan1_kernel(const int* __restrict__ deg,
    int* __restrict__ rowStart, int* __restrict__ blockSums)
{
  __shared__ int buf[256];
  int i = blockIdx.x*256 + threadIdx.x;
  int v = (i < NN) ? deg[i] : 0;
  buf[threadIdx.x] = v;
  __syncthreads();
  for (int off = 1; off < 256; off <<= 1){
    int t = (threadIdx.x >= off) ? buf[threadIdx.x - off] : 0;
    __syncthreads();
    buf[threadIdx.x] += t;
    __syncthreads();
  }
  if (i < NN) rowStart[i] = buf[threadIdx.x] - v;
  if (threadIdx.x == 255) blockSums[blockIdx.x] = buf[255];
}

// merged: every block redundantly scans blockSums, then applies its offset
__global__ void __launch_bounds__(256) scan23_kernel(int* __restrict__ rowStart,
    const int* __restrict__ blockSums, int* __restrict__ cursor)
{
  __shared__ int buf[256];
  int v = (threadIdx.x < NB) ? blockSums[threadIdx.x] : 0;
  buf[threadIdx.x] = v;
  __syncthreads();
  for (int off = 1; off < 256; off <<= 1){
    int t = (threadIdx.x >= off) ? buf[threadIdx.x - off] : 0;
    __syncthreads();
    buf[threadIdx.x] += t;
    __syncthreads();
  }
  int myOff = (blockIdx.x == 0) ? 0 : buf[blockIdx.x - 1];
  int i = blockIdx.x*256 + threadIdx.x;
  if (i < NN){
    int val = rowStart[i] + myOff;
    rowStart[i] = val;
    cursor[i]   = val;
  }
  if (i == 0) rowStart[NN] = EP;
}

__global__ void __launch_bounds__(256) scatter_kernel(const int* __restrict__ ei,
    int* __restrict__ cursor, unsigned short* __restrict__ srcL)
{
  int e = blockIdx.x*256 + threadIdx.x;
  if (e >= EP) return;
  int s, d;
  if (e < EE){ s = ei[e]; d = ei[EE + e]; } else { s = d = e - EE; }
  int pos = atomicAdd(&cursor[d], 1);
  srcL[pos] = (unsigned short)s;
}

// ---------------- MFMA GEMM: h = x@W (bf16 out) + al dots via 9th col tile ----------------
// 64 rows/block, 4 waves, 16 rows/wave. A: x rows as bf16 frags; B: pre-packed Wmf in LDS.
template<bool XFIXBF16, int H>
__global__ void __launch_bounds__(256) gemm_mfma_kernel(const void* __restrict__ Xv,
    const unsigned short* __restrict__ Wmf,
    unsigned short* __restrict__ Hout,
    float* __restrict__ alS, float* __restrict__ alD,
    const int* __restrict__ flag)
{
  __shared__ unsigned short wl[36*64*8];    // 36 KB = 2304 uint4
  const int tid = threadIdx.x;
  {
    const uint4* src = (const uint4*)Wmf;
    uint4* dst = (uint4*)wl;
    #pragma unroll
    for (int i = 0; i < 9; i++)             // 9*256 = 2304 uint4 — FULL copy (was the r7 bug)
      dst[tid + i*256] = src[tid + i*256];
  }
  const int lane = tid & 63, wv = tid >> 6;
  const int r0 = blockIdx.x*64 + wv*16;
  const int m = lane & 15, quad = lane >> 4;
  const int row = r0 + m;
  const bool rowOK = row < NN;

  short8 a[4];
  const bool xbf = XFIXBF16 || (flag[0] == 0);
  if (xbf){
    const short* Xb = (const short*)Xv;
    #pragma unroll
    for (int kb = 0; kb < 4; kb++){
      if (rowOK) a[kb] = *(const short8*)&Xb[(size_t)row*DD + kb*32 + quad*8];
      else       a[kb] = (short8){0,0,0,0,0,0,0,0};
    }
  } else {
    const float* Xf = (const float*)Xv;
    #pragma unroll
    for (int kb = 0; kb < 4; kb++){
      if (rowOK){
        float4 f0 = *(const float4*)&Xf[(size_t)row*DD + kb*32 + quad*8];
        float4 f1 = *(const float4*)&Xf[(size_t)row*DD + kb*32 + quad*8 + 4];
        union { short8 v; unsigned short u[8]; } cv;
        cv.u[0]=f2bs(f0.x); cv.u[1]=f2bs(f0.y); cv.u[2]=f2bs(f0.z); cv.u[3]=f2bs(f0.w);
        cv.u[4]=f2bs(f1.x); cv.u[5]=f2bs(f1.y); cv.u[6]=f2bs(f1.z); cv.u[7]=f2bs(f1.w);
        a[kb] = cv.v;
      } else a[kb] = (short8){0,0,0,0,0,0,0,0};
    }
  }
  __syncthreads();

  f32x4 acc[9];
  #pragma unroll
  for (int c = 0; c < 9; c++) acc[c] = (f32x4){0.f,0.f,0.f,0.f};
  #pragma unroll
  for (int c = 0; c < 9; c++){
    #pragma unroll
    for (int kb = 0; kb < 4; kb++){
      short8 b = *(const short8*)&wl[((c*4 + kb)*64 + lane)*8];
      acc[c] = __builtin_amdgcn_mfma_f32_16x16x32_bf16(a[kb], b, acc[c], 0, 0, 0);
    }
  }

  // h store: D layout col=lane&15, row=quad*4+reg  [m89/m91-verified]
  #pragma unroll
  for (int c = 0; c < 8; c++){
    #pragma unroll
    for (int r = 0; r < 4; r++){
      int rw = r0 + quad*4 + r;
      if (rw < NN) Hout[(size_t)rw*DD + c*16 + m] = f2bs(acc[c][r]);
    }
  }
  // al store from tile 8
  #pragma unroll
  for (int r = 0; r < 4; r++){
    int rw = r0 + quad*4 + r;
    if (rw < NN){
      float v = acc[8][r];
      if (H == 8){
        if (m < 8) alS[rw*8 + m]       = v;
        else       alD[rw*8 + (m - 8)] = v;
      } else {
        if (m == 0)      alS[rw] = v;
        else if (m == 1) alD[rw] = v;
      }
    }
  }
}

// ---------------- fused: softmax (phase-split) + gather-aggregate + bias + LN (+ELU) ----------------
// one wave per dst node; lane covers channels 2*lane, 2*lane+1.
// Phase 1: 64 lanes compute weights for 64/H edges x H heads (one exp per (edge,head)).
// Phase 2: weights + src ids broadcast via shuffle; gather hB + fma.
template<int H, bool FINAL>
__global__ void __launch_bounds__(256) aggln_kernel(
    const int* __restrict__ rowStart, const unsigned short* __restrict__ srcL,
    const float* __restrict__ alS, const float* __restrict__ alD,
    const unsigned short* __restrict__ hB,
    const void* __restrict__ b, const void* __restrict__ g, const void* __restrict__ be,
    void* __restrict__ outv, const int* __restrict__ flag)
{
  const int f    = flag[0];
  const int lane = threadIdx.x & 63;
  const int d    = blockIdx.x*4 + (threadIdx.x >> 6);
  const int c0   = lane*2;
  const int hd2  = (H == 8) ? (lane >> 3) : 0;       // head for my channels
  const int h1   = (H == 8) ? (lane & 7)  : 0;       // head for phase-1 duty
  const int EPB  = 64 / H;                           // edges per phase-1 batch
  const int start = rowStart[d], end = rowStart[d+1];
  const float aldP1 = alD[d*H + h1];

  float ssum = 0.f, a0 = 0.f, a1 = 0.f;
  for (int base = start; base < end; base += 64){
    const int cnt = min(64, end - base);
    int myS = (base + lane < end) ? (int)srcL[base + lane] : 0;
    for (int j0 = 0; j0 < cnt; j0 += EPB){
      // phase 1: weight for (edge j0 + lane/H, head lane%H)
      int eIdx = min(j0 + lane/H, cnt - 1);
      int sW = __shfl(myS, eIdx, 64);
      float el = alS[sW*H + h1] + aldP1;
      el = el > 0.f ? el : 0.2f*el;
      float wv = __expf(fminf(el, 80.f));
      // phase 2
      int nE = min(EPB, cnt - j0);
      if (nE == EPB){
        #pragma unroll
        for (int j = 0; j < EPB; j++){
          int s = __shfl(myS, j0 + j, 64);
          float w = __shfl(wv, j*H + hd2, 64);
          ushort2 hv = *(const ushort2*)&hB[(size_t)s*DD + c0];
          ssum += w;
          a0 = fmaf(bfu(hv.x), w, a0);
          a1 = fmaf(bfu(hv.y), w, a1);
        }
      } else {
        for (int j = 0; j < nE; j++){
          int s = __shfl(myS, j0 + j, 64);
          float w = __shfl(wv, j*H + hd2, 64);
          ushort2 hv = *(const ushort2*)&hB[(size_t)s*DD + c0];
          ssum += w;
          a0 = fmaf(bfu(hv.x), w, a0);
          a1 = fmaf(bfu(hv.y), w, a1);
        }
      }
    }
  }
  const float sinv = 1.f / ssum;

  // bias + LayerNorm across the wave's 128 channels
  float v0 = a0*sinv + ldf(b, c0, f), v1 = a1*sinv + ldf(b, c0+1, f);
  float s2 = v0 + v1;
  #pragma unroll
  for (int off = 32; off >= 1; off >>= 1) s2 += __shfl_xor(s2, off, 64);
  float mu = s2 * (1.0f/128.0f);
  float d0 = v0 - mu, d1 = v1 - mu;
  float q = d0*d0 + d1*d1;
  #pragma unroll
  for (int off = 32; off >= 1; off >>= 1) q += __shfl_xor(q, off, 64);
  float r = rsqrtf(q*(1.0f/128.0f) + 1e-5f);
  float y0 = d0*r*ldf(g, c0, f)   + ldf(be, c0, f);
  float y1 = d1*r*ldf(g, c0+1, f) + ldf(be, c0+1, f);
  if (FINAL){
    if (f){
      *(float2*)&((float*)outv)[(size_t)d*DD + c0] = make_float2(y0, y1);
    } else {
      ushort2 o; o.x = f2bs(y0); o.y = f2bs(y1);
      *(ushort2*)&((unsigned short*)outv)[(size_t)d*DD + c0] = o;
    }
  } else {
    y0 = y0 > 0.f ? y0 : __expf(y0) - 1.f;   // ELU
    y1 = y1 > 0.f ? y1 : __expf(y1) - 1.f;
    ushort2 o; o.x = f2bs(y0); o.y = f2bs(y1);
    *(ushort2*)&((unsigned short*)outv)[(size_t)d*DD + c0] = o;
  }
}

// ---------------- host-side layer driver ----------------
template<bool XFIXBF16, int H, bool FINAL>
static void run_layer(const void* x, const unsigned short* WmfL,
                      const void* b, const void* g, const void* be,
                      const int* rowStart, const unsigned short* srcL,
                      unsigned short* hB, float* alS, float* alD,
                      void* outv, const int* flag, hipStream_t stream)
{
  gemm_mfma_kernel<XFIXBF16, H><<<782, 256, 0, stream>>>(x, WmfL, hB, alS, alD, flag);
  aggln_kernel<H, FINAL><<<12500, 256, 0, stream>>>(rowStart, srcL, alS, alD, hB,
                                                    b, g, be, outv, flag);
}

extern "C" void kernel_launch(void* const* d_in, const int* in_sizes, int n_in,
                              void* d_out, int out_size, void* d_ws, size_t ws_size,
                              hipStream_t stream)
{
  // ws layout (~31.5 MB)
  char* w = (char*)d_ws;
  int*   flag     = (int*)w;                     w += 256;
  unsigned short* accB = (unsigned short*)w;     w += (size_t)NN*DD*2;   // 12.8 MB (bf16 x-next)
  unsigned short* hB   = (unsigned short*)w;     w += (size_t)NN*DD*2;   // 12.8 MB (bf16 h)
  float* alS      = (float*)w;                   w += (size_t)NN*8*4;    // 1.6 MB
  float* alD      = (float*)w;                   w += (size_t)NN*8*4;    // 1.6 MB
  unsigned short* Wmf = (unsigned short*)w;      w += (size_t)3*36*64*8*2; // 216 KB
  int*   deg      = (int*)w;                     w += (size_t)NN*4;      // 200 KB
  int*   rowStart = (int*)w;                     w += (size_t)(NN+1)*4;  // 200 KB
  int*   cursor   = (int*)w;                     w += (size_t)NN*4;      // 200 KB
  int*   blockSums= (int*)w;                     w += 1024;
  unsigned short* srcL = (unsigned short*)w;     w += (size_t)EP*2;      // 1.7 MB
  if (ws_size < (size_t)(w - (char*)d_ws)) return;

  const void* x  = d_in[0];
  const int*  ei = (const int*)d_in[1];
  const void *W0=d_in[2], *as0=d_in[3], *ad0=d_in[4], *b0=d_in[5], *g0=d_in[6], *be0=d_in[7];
  const void *W1=d_in[8], *as1=d_in[9], *ad1=d_in[10],*b1=d_in[11],*g1=d_in[12],*be1=d_in[13];
  const void *W2=d_in[14],*as2=d_in[15],*ad2=d_in[16],*b2=d_in[17],*g2=d_in[18],*be2=d_in[19];

  probe_zero_kernel<<<NB, 256, 0, stream>>>((const unsigned short*)x, flag, deg);
  packw_kernel<<<27, 256, 0, stream>>>(W0, as0, ad0, W1, as1, ad1, W2, as2, ad2, Wmf, flag);
  hist_kernel<<<(EP + 255)/256, 256, 0, stream>>>(ei, deg);
  scan1_kernel<<<NB, 256, 0, stream>>>(deg, rowStart, blockSums);
  scan23_kernel<<<NB, 256, 0, stream>>>(rowStart, blockSums, cursor);
  scatter_kernel<<<(EP + 255)/256, 256, 0, stream>>>(ei, cursor, srcL);

  // layer 0: x = probed dtype, 8 heads, ELU -> accB (bf16)
  run_layer<false, 8, false>(x,    Wmf,            b0, g0, be0,
                             rowStart, srcL, hB, alS, alD, accB, flag, stream);
  // layer 1: x = accB (bf16), 8 heads, ELU -> accB
  run_layer<true, 8, false>(accB, Wmf + (size_t)36*64*8,   b1, g1, be1,
                             rowStart, srcL, hB, alS, alD, accB, flag, stream);
  // layer 2: x = accB (bf16), 1 head, LN only -> d_out (per-flag dtype)
  run_layer<true, 1, true>(accB, Wmf + (size_t)2*36*64*8,  b2, g2, be2,
                             rowStart, srcL, hB, alS, alD, d_out, flag, stream);
}

// Round 9
// 422.672 us; speedup vs baseline: 7.7074x; 1.1303x over previous
//
#include <hip/hip_runtime.h>
#include <hip/hip_bf16.h>

#define NN 50000
#define EE 800000
#define EP 850000   // EE + NN self-loops
#define DD 128
#define NB 196      // ceil(NN/256)

typedef __attribute__((ext_vector_type(8))) short short8;
typedef __attribute__((ext_vector_type(4))) float f32x4;

__device__ __forceinline__ float bf2f(__hip_bfloat16 x){ return __bfloat162float(x); }
__device__ __forceinline__ float bfu(unsigned short u){ return __uint_as_float(((unsigned)u)<<16); }
__device__ __forceinline__ unsigned short f2bs(float x){
  __hip_bfloat16 h = __float2bfloat16(x);
  union { __hip_bfloat16 h; unsigned short u; } cv; cv.h = h; return cv.u;
}
// load float tensor element i, dtype selected at runtime (f32 ? float : bf16)
__device__ __forceinline__ float ldf(const void* p, size_t i, int f32){
  return f32 ? ((const float*)p)[i] : bf2f(((const __hip_bfloat16*)p)[i]);
}

// ---------------- probe dtype (block 0) + zero deg (all blocks) ----------------
__global__ void __launch_bounds__(256) probe_zero_kernel(const unsigned short* __restrict__ xu,
    int* __restrict__ flag, int* __restrict__ deg)
{
  int i = blockIdx.x*256 + threadIdx.x;
  if (i < NN) deg[i] = 0;
  if (blockIdx.x == 0){
    __shared__ int sc[256];
    int c = 0;
    for (int k = threadIdx.x; k < 32768; k += 256)
      if ((xu[k] & 0x7F80) == 0x7F80) c++;        // bf16 inf/nan exponent pattern
    sc[threadIdx.x] = c;
    __syncthreads();
    for (int s = 128; s > 0; s >>= 1){
      if (threadIdx.x < s) sc[threadIdx.x] += sc[threadIdx.x + s];
      __syncthreads();
    }
    if (threadIdx.x == 0) flag[0] = (sc[0] > 16) ? 1 : 0;   // 1 => tensors are float32
  }
}

// ---------------- W@a_src / W@a_dst -> tile 8 of Wmf, one wave per (layer,k) ----------------
// tile 8 fragment: Wmf[(L*36+32+kb)*64 + quad*16 + n][j], k = kb*32+quad*8+j,
// n<8 -> (W@a_src)[k][head n], n>=8 -> (W@a_dst)[k][head n-8] (H=1: n==0/1 only)
__global__ void __launch_bounds__(64) wa_kernel(
    const void* __restrict__ W0, const void* __restrict__ as0, const void* __restrict__ ad0,
    const void* __restrict__ W1, const void* __restrict__ as1, const void* __restrict__ ad1,
    const void* __restrict__ W2, const void* __restrict__ as2, const void* __restrict__ ad2,
    unsigned short* __restrict__ Wmf, const int* __restrict__ flag)
{
  const int f = flag[0];
  const int b = blockIdx.x;             // 0..383
  const int L = b >> 7, k = b & 127;
  const void *W, *as, *ad; int H;
  if (L == 0){ W = W0; as = as0; ad = ad0; H = 8; }
  else if (L == 1){ W = W1; as = as1; ad = ad1; H = 8; }
  else { W = W2; as = as2; ad = ad2; H = 1; }
  const int lane = threadIdx.x;
  const int c0 = lane*2;
  float w0 = ldf(W, (size_t)k*DD + c0,     f);
  float w1 = ldf(W, (size_t)k*DD + c0 + 1, f);
  float ps = w0*ldf(as, c0, f) + w1*ldf(as, c0+1, f);
  float pd = w0*ldf(ad, c0, f) + w1*ldf(ad, c0+1, f);
  if (H == 8){
    #pragma unroll
    for (int off = 1; off <= 4; off <<= 1){   // reduce within 8-lane head groups
      ps += __shfl_xor(ps, off, 64);
      pd += __shfl_xor(pd, off, 64);
    }
  } else {
    #pragma unroll
    for (int off = 1; off <= 32; off <<= 1){  // full-wave reduce
      ps += __shfl_xor(ps, off, 64);
      pd += __shfl_xor(pd, off, 64);
    }
  }
  // branchless pick: lane n<8 takes head-n src sum (group leader lane n*8), n in 8..15 dst
  int srcLane = (lane < 8) ? lane*8 : (lane < 16 ? (lane-8)*8 : 0);
  float vs = __shfl(ps, srcLane, 64);
  float vd = __shfl(pd, srcLane, 64);
  float myv;
  if (H == 8) myv = (lane < 8) ? vs : (lane < 16 ? vd : 0.f);
  else        myv = (lane == 0) ? ps : (lane == 1 ? pd : 0.f);
  const int kb = k >> 5, quad = (k >> 3) & 3, j = k & 7;
  if (lane < 16)
    Wmf[(((size_t)L*36 + 32 + kb)*64 + quad*16 + lane)*8 + j] = f2bs(myv);
}

// ---------------- pack W (tiles 0..7) into MFMA B-fragment order ----------------
// Wmf[layer][t=c*4+kb][lane][j] = W[kb*32+(lane>>4)*8+j][c*16+(lane&15)]
__global__ void __launch_bounds__(256) packw_kernel(
    const void* __restrict__ W0, const void* __restrict__ W1, const void* __restrict__ W2,
    unsigned short* __restrict__ Wmf, const int* __restrict__ flag)
{
  const int f = flag[0];
  const int L = blockIdx.x >> 3, seg = blockIdx.x & 7;
  const void* W = (L == 0) ? W0 : (L == 1) ? W1 : W2;
  int idx = seg*256 + threadIdx.x;          // 0..2047
  int t = idx >> 6, lane = idx & 63;        // t 0..31
  int c = t >> 2, kb = t & 3;
  int m = lane & 15, quad = lane >> 4;
  unsigned short out[8];
  #pragma unroll
  for (int j = 0; j < 8; j++){
    int k = kb*32 + quad*8 + j;
    out[j] = f2bs(ldf(W, (size_t)k*DD + c*16 + m, f));
  }
  *(uint4*)&Wmf[(((size_t)L*36 + t)*64 + lane)*8] = *(const uint4*)out;
}

// ---------------- CSR build ----------------
__global__ void __launch_bounds__(256) hist_kernel(const int* __restrict__ ei, int* __restrict__ deg)
{
  int e = blockIdx.x*256 + threadIdx.x;
  if (e >= EP) return;
  int d = (e < EE) ? ei[EE + e] : e - EE;
  atomicAdd(&deg[d], 1);
}

__global__ void __launch_bounds__(256) scan1_kernel(const int* __restrict__ deg,
    int* __restrict__ rowStart, int* __restrict__ blockSums)
{
  __shared__ int buf[256];
  int i = blockIdx.x*256 + threadIdx.x;
  int v = (i < NN) ? deg[i] : 0;
  buf[threadIdx.x] = v;
  __syncthreads();
  for (int off = 1; off < 256; off <<= 1){
    int t = (threadIdx.x >= off) ? buf[threadIdx.x - off] : 0;
    __syncthreads();
    buf[threadIdx.x] += t;
    __syncthreads();
  }
  if (i < NN) rowStart[i] = buf[threadIdx.x] - v;
  if (threadIdx.x == 255) blockSums[blockIdx.x] = buf[255];
}

// merged: every block redundantly scans blockSums, then applies its offset
__global__ void __launch_bounds__(256) scan23_kernel(int* __restrict__ rowStart,
    const int* __restrict__ blockSums, int* __restrict__ cursor)
{
  __shared__ int buf[256];
  int v = (threadIdx.x < NB) ? blockSums[threadIdx.x] : 0;
  buf[threadIdx.x] = v;
  __syncthreads();
  for (int off = 1; off < 256; off <<= 1){
    int t = (threadIdx.x >= off) ? buf[threadIdx.x - off] : 0;
    __syncthreads();
    buf[threadIdx.x] += t;
    __syncthreads();
  }
  int myOff = (blockIdx.x == 0) ? 0 : buf[blockIdx.x - 1];
  int i = blockIdx.x*256 + threadIdx.x;
  if (i < NN){
    int val = rowStart[i] + myOff;
    rowStart[i] = val;
    cursor[i]   = val;
  }
  if (i == 0) rowStart[NN] = EP;
}

__global__ void __launch_bounds__(256) scatter_kernel(const int* __restrict__ ei,
    int* __restrict__ cursor, unsigned short* __restrict__ srcL)
{
  int e = blockIdx.x*256 + threadIdx.x;
  if (e >= EP) return;
  int s, d;
  if (e < EE){ s = ei[e]; d = ei[EE + e]; } else { s = d = e - EE; }
  int pos = atomicAdd(&cursor[d], 1);
  srcL[pos] = (unsigned short)s;
}

// ---------------- MFMA GEMM: h = x@W (bf16 out) + al dots via 9th col tile ----------------
// 64 rows/block, 4 waves, 16 rows/wave. A: x rows as bf16 frags; B: pre-packed Wmf in LDS.
template<bool XFIXBF16, int H>
__global__ void __launch_bounds__(256) gemm_mfma_kernel(const void* __restrict__ Xv,
    const unsigned short* __restrict__ Wmf,
    unsigned short* __restrict__ Hout,
    float* __restrict__ alS, float* __restrict__ alD,
    const int* __restrict__ flag)
{
  __shared__ unsigned short wl[36*64*8];    // 36 KB = 2304 uint4
  const int tid = threadIdx.x;
  {
    const uint4* src = (const uint4*)Wmf;
    uint4* dst = (uint4*)wl;
    #pragma unroll
    for (int i = 0; i < 9; i++)             // 9*256 = 2304 uint4 — full copy
      dst[tid + i*256] = src[tid + i*256];
  }
  const int lane = tid & 63, wv = tid >> 6;
  const int r0 = blockIdx.x*64 + wv*16;
  const int m = lane & 15, quad = lane >> 4;
  const int row = r0 + m;
  const bool rowOK = row < NN;

  short8 a[4];
  const bool xbf = XFIXBF16 || (flag[0] == 0);
  if (xbf){
    const short* Xb = (const short*)Xv;
    #pragma unroll
    for (int kb = 0; kb < 4; kb++){
      if (rowOK) a[kb] = *(const short8*)&Xb[(size_t)row*DD + kb*32 + quad*8];
      else       a[kb] = (short8){0,0,0,0,0,0,0,0};
    }
  } else {
    const float* Xf = (const float*)Xv;
    #pragma unroll
    for (int kb = 0; kb < 4; kb++){
      if (rowOK){
        float4 f0 = *(const float4*)&Xf[(size_t)row*DD + kb*32 + quad*8];
        float4 f1 = *(const float4*)&Xf[(size_t)row*DD + kb*32 + quad*8 + 4];
        union { short8 v; unsigned short u[8]; } cv;
        cv.u[0]=f2bs(f0.x); cv.u[1]=f2bs(f0.y); cv.u[2]=f2bs(f0.z); cv.u[3]=f2bs(f0.w);
        cv.u[4]=f2bs(f1.x); cv.u[5]=f2bs(f1.y); cv.u[6]=f2bs(f1.z); cv.u[7]=f2bs(f1.w);
        a[kb] = cv.v;
      } else a[kb] = (short8){0,0,0,0,0,0,0,0};
    }
  }
  __syncthreads();

  f32x4 acc[9];
  #pragma unroll
  for (int c = 0; c < 9; c++) acc[c] = (f32x4){0.f,0.f,0.f,0.f};
  #pragma unroll
  for (int c = 0; c < 9; c++){
    #pragma unroll
    for (int kb = 0; kb < 4; kb++){
      short8 b = *(const short8*)&wl[((c*4 + kb)*64 + lane)*8];
      acc[c] = __builtin_amdgcn_mfma_f32_16x16x32_bf16(a[kb], b, acc[c], 0, 0, 0);
    }
  }

  // h store: D layout col=lane&15, row=quad*4+reg  [m89/m91-verified]
  #pragma unroll
  for (int c = 0; c < 8; c++){
    #pragma unroll
    for (int r = 0; r < 4; r++){
      int rw = r0 + quad*4 + r;
      if (rw < NN) Hout[(size_t)rw*DD + c*16 + m] = f2bs(acc[c][r]);
    }
  }
  // al store from tile 8
  #pragma unroll
  for (int r = 0; r < 4; r++){
    int rw = r0 + quad*4 + r;
    if (rw < NN){
      float v = acc[8][r];
      if (H == 8){
        if (m < 8) alS[rw*8 + m]       = v;
        else       alD[rw*8 + (m - 8)] = v;
      } else {
        if (m == 0)      alS[rw] = v;
        else if (m == 1) alD[rw] = v;
      }
    }
  }
}

// ---------------- fused: softmax (phase-split) + gather-aggregate + bias + LN (+ELU) ----------------
template<int H, bool FINAL>
__global__ void __launch_bounds__(256) aggln_kernel(
    const int* __restrict__ rowStart, const unsigned short* __restrict__ srcL,
    const float* __restrict__ alS, const float* __restrict__ alD,
    const unsigned short* __restrict__ hB,
    const void* __restrict__ b, const void* __restrict__ g, const void* __restrict__ be,
    void* __restrict__ outv, const int* __restrict__ flag)
{
  const int f    = flag[0];
  const int lane = threadIdx.x & 63;
  const int d    = blockIdx.x*4 + (threadIdx.x >> 6);
  const int c0   = lane*2;
  const int hd2  = (H == 8) ? (lane >> 3) : 0;       // head for my channels
  const int h1   = (H == 8) ? (lane & 7)  : 0;       // head for phase-1 duty
  const int EPB  = 64 / H;                           // edges per phase-1 batch
  const int start = rowStart[d], end = rowStart[d+1];
  const float aldP1 = alD[d*H + h1];

  float ssum = 0.f, a0 = 0.f, a1 = 0.f;
  for (int base = start; base < end; base += 64){
    const int cnt = min(64, end - base);
    int myS = (base + lane < end) ? (int)srcL[base + lane] : 0;
    for (int j0 = 0; j0 < cnt; j0 += EPB){
      // phase 1: weight for (edge j0 + lane/H, head lane%H)
      int eIdx = min(j0 + lane/H, cnt - 1);
      int sW = __shfl(myS, eIdx, 64);
      float el = alS[sW*H + h1] + aldP1;
      el = el > 0.f ? el : 0.2f*el;
      float wv = __expf(fminf(el, 80.f));
      // phase 2
      int nE = min(EPB, cnt - j0);
      if (nE == EPB){
        #pragma unroll
        for (int j = 0; j < EPB; j++){
          int s = __shfl(myS, j0 + j, 64);
          float w = __shfl(wv, j*H + hd2, 64);
          ushort2 hv = *(const ushort2*)&hB[(size_t)s*DD + c0];
          ssum += w;
          a0 = fmaf(bfu(hv.x), w, a0);
          a1 = fmaf(bfu(hv.y), w, a1);
        }
      } else {
        for (int j = 0; j < nE; j++){
          int s = __shfl(myS, j0 + j, 64);
          float w = __shfl(wv, j*H + hd2, 64);
          ushort2 hv = *(const ushort2*)&hB[(size_t)s*DD + c0];
          ssum += w;
          a0 = fmaf(bfu(hv.x), w, a0);
          a1 = fmaf(bfu(hv.y), w, a1);
        }
      }
    }
  }
  const float sinv = 1.f / ssum;

  // bias + LayerNorm across the wave's 128 channels
  float v0 = a0*sinv + ldf(b, c0, f), v1 = a1*sinv + ldf(b, c0+1, f);
  float s2 = v0 + v1;
  #pragma unroll
  for (int off = 32; off >= 1; off >>= 1) s2 += __shfl_xor(s2, off, 64);
  float mu = s2 * (1.0f/128.0f);
  float d0 = v0 - mu, d1 = v1 - mu;
  float q = d0*d0 + d1*d1;
  #pragma unroll
  for (int off = 32; off >= 1; off >>= 1) q += __shfl_xor(q, off, 64);
  float r = rsqrtf(q*(1.0f/128.0f) + 1e-5f);
  float y0 = d0*r*ldf(g, c0, f)   + ldf(be, c0, f);
  float y1 = d1*r*ldf(g, c0+1, f) + ldf(be, c0+1, f);
  if (FINAL){
    if (f){
      *(float2*)&((float*)outv)[(size_t)d*DD + c0] = make_float2(y0, y1);
    } else {
      ushort2 o; o.x = f2bs(y0); o.y = f2bs(y1);
      *(ushort2*)&((unsigned short*)outv)[(size_t)d*DD + c0] = o;
    }
  } else {
    y0 = y0 > 0.f ? y0 : __expf(y0) - 1.f;   // ELU
    y1 = y1 > 0.f ? y1 : __expf(y1) - 1.f;
    ushort2 o; o.x = f2bs(y0); o.y = f2bs(y1);
    *(ushort2*)&((unsigned short*)outv)[(size_t)d*DD + c0] = o;
  }
}

// ---------------- host-side layer driver ----------------
template<bool XFIXBF16, int H, bool FINAL>
static void run_layer(const void* x, const unsigned short* WmfL,
                      const void* b, const void* g, const void* be,
                      const int* rowStart, const unsigned short* srcL,
                      unsigned short* hB, float* alS, float* alD,
                      void* outv, const int* flag, hipStream_t stream)
{
  gemm_mfma_kernel<XFIXBF16, H><<<782, 256, 0, stream>>>(x, WmfL, hB, alS, alD, flag);
  aggln_kernel<H, FINAL><<<12500, 256, 0, stream>>>(rowStart, srcL, alS, alD, hB,
                                                    b, g, be, outv, flag);
}

extern "C" void kernel_launch(void* const* d_in, const int* in_sizes, int n_in,
                              void* d_out, int out_size, void* d_ws, size_t ws_size,
                              hipStream_t stream)
{
  // ws layout (~31.5 MB)
  char* w = (char*)d_ws;
  int*   flag     = (int*)w;                     w += 256;
  unsigned short* accB = (unsigned short*)w;     w += (size_t)NN*DD*2;   // 12.8 MB (bf16 x-next)
  unsigned short* hB   = (unsigned short*)w;     w += (size_t)NN*DD*2;   // 12.8 MB (bf16 h)
  float* alS      = (float*)w;                   w += (size_t)NN*8*4;    // 1.6 MB
  float* alD      = (float*)w;                   w += (size_t)NN*8*4;    // 1.6 MB
  unsigned short* Wmf = (unsigned short*)w;      w += (size_t)3*36*64*8*2; // 216 KB
  int*   deg      = (int*)w;                     w += (size_t)NN*4;      // 200 KB
  int*   rowStart = (int*)w;                     w += (size_t)(NN+1)*4;  // 200 KB
  int*   cursor   = (int*)w;                     w += (size_t)NN*4;      // 200 KB
  int*   blockSums= (int*)w;                     w += 1024;
  unsigned short* srcL = (unsigned short*)w;     w += (size_t)EP*2;      // 1.7 MB
  if (ws_size < (size_t)(w - (char*)d_ws)) return;

  const void* x  = d_in[0];
  const int*  ei = (const int*)d_in[1];
  const void *W0=d_in[2], *as0=d_in[3], *ad0=d_in[4], *b0=d_in[5], *g0=d_in[6], *be0=d_in[7];
  const void *W1=d_in[8], *as1=d_in[9], *ad1=d_in[10],*b1=d_in[11],*g1=d_in[12],*be1=d_in[13];
  const void *W2=d_in[14],*as2=d_in[15],*ad2=d_in[16],*b2=d_in[17],*g2=d_in[18],*be2=d_in[19];

  probe_zero_kernel<<<NB, 256, 0, stream>>>((const unsigned short*)x, flag, deg);
  wa_kernel<<<384, 64, 0, stream>>>(W0, as0, ad0, W1, as1, ad1, W2, as2, ad2, Wmf, flag);
  packw_kernel<<<24, 256, 0, stream>>>(W0, W1, W2, Wmf, flag);
  hist_kernel<<<(EP + 255)/256, 256, 0, stream>>>(ei, deg);
  scan1_kernel<<<NB, 256, 0, stream>>>(deg, rowStart, blockSums);
  scan23_kernel<<<NB, 256, 0, stream>>>(rowStart, blockSums, cursor);
  scatter_kernel<<<(EP + 255)/256, 256, 0, stream>>>(ei, cursor, srcL);

  // layer 0: x = probed dtype, 8 heads, ELU -> accB (bf16)
  run_layer<false, 8, false>(x,    Wmf,            b0, g0, be0,
                             rowStart, srcL, hB, alS, alD, accB, flag, stream);
  // layer 1: x = accB (bf16), 8 heads, ELU -> accB
  run_layer<true, 8, false>(accB, Wmf + (size_t)36*64*8,   b1, g1, be1,
                             rowStart, srcL, hB, alS, alD, accB, flag, stream);
  // layer 2: x = accB (bf16), 1 head, LN only -> d_out (per-flag dtype)
  run_layer<true, 1, true>(accB, Wmf + (size_t)2*36*64*8,  b2, g2, be2,
                             rowStart, srcL, hB, alS, alD, d_out, flag, stream);
}

// Round 10
// 349.762 us; speedup vs baseline: 9.3140x; 1.2085x over previous
//
#include <hip/hip_runtime.h>
#include <hip/hip_bf16.h>

#define NN 50000
#define EE 800000
#define EP 850000   // EE + NN self-loops
#define DD 128
#define NB 196      // ceil(NN/256)

typedef __attribute__((ext_vector_type(8))) short short8;
typedef __attribute__((ext_vector_type(4))) float f32x4;

__device__ __forceinline__ float bfu(unsigned short u){ return __uint_as_float(((unsigned)u)<<16); }
__device__ __forceinline__ unsigned short f2bs(float x){
  __hip_bfloat16 h = __float2bfloat16(x);
  union { __hip_bfloat16 h; unsigned short u; } cv; cv.h = h; return cv.u;
}

// ---------------- prep: zero deg (all blocks) + pack W tiles (blocks 0..23)
// ---------------- + W@a fragments (blocks 24..119) --------------------------
// Wmf[layer][t=c*4+kb][lane][j] = W[kb*32+(lane>>4)*8+j][c*16+(lane&15)]  (c<8)
// tile 8: n=lane&15: n<8 -> (W@a_src)[k][head n], n>=8 -> (W@a_dst)[k][head n-8]
__global__ void __launch_bounds__(256) prep_kernel(
    const float* __restrict__ W0, const float* __restrict__ as0, const float* __restrict__ ad0,
    const float* __restrict__ W1, const float* __restrict__ as1, const float* __restrict__ ad1,
    const float* __restrict__ W2, const float* __restrict__ as2, const float* __restrict__ ad2,
    unsigned short* __restrict__ Wmf, int* __restrict__ deg)
{
  const int tid = threadIdx.x;
  {
    int i = blockIdx.x*256 + tid;
    if (i < NN) deg[i] = 0;
  }
  if (blockIdx.x < 24){
    // W reformat, tiles 0..31
    const int L = blockIdx.x >> 3, seg = blockIdx.x & 7;
    const float* W = (L == 0) ? W0 : (L == 1) ? W1 : W2;
    int idx = seg*256 + tid;                  // 0..2047
    int t = idx >> 6, lane = idx & 63;        // t 0..31
    int c = t >> 2, kb = t & 3;
    int m = lane & 15, quad = lane >> 4;
    unsigned short out[8];
    #pragma unroll
    for (int j = 0; j < 8; j++){
      int k = kb*32 + quad*8 + j;
      out[j] = f2bs(W[(size_t)k*DD + c*16 + m]);
    }
    *(uint4*)&Wmf[(((size_t)L*36 + t)*64 + lane)*8] = *(const uint4*)out;
  } else if (blockIdx.x < 120){
    // W@a_src / W@a_dst -> tile 8; one wave per (layer,k)
    const int q = blockIdx.x - 24;
    const int wIdx = q*4 + (tid >> 6);        // 0..383
    const int L = wIdx >> 7, k = wIdx & 127;
    const float *W, *as, *ad; int H;
    if (L == 0){ W = W0; as = as0; ad = ad0; H = 8; }
    else if (L == 1){ W = W1; as = as1; ad = ad1; H = 8; }
    else { W = W2; as = as2; ad = ad2; H = 1; }
    const int lane = tid & 63;
    const int c0 = lane*2;
    float w0 = W[(size_t)k*DD + c0];
    float w1 = W[(size_t)k*DD + c0 + 1];
    float ps = w0*as[c0] + w1*as[c0+1];
    float pd = w0*ad[c0] + w1*ad[c0+1];
    if (H == 8){
      #pragma unroll
      for (int off = 1; off <= 4; off <<= 1){   // reduce within 8-lane head groups
        ps += __shfl_xor(ps, off, 64);
        pd += __shfl_xor(pd, off, 64);
      }
    } else {
      #pragma unroll
      for (int off = 1; off <= 32; off <<= 1){  // full-wave reduce
        ps += __shfl_xor(ps, off, 64);
        pd += __shfl_xor(pd, off, 64);
      }
    }
    int srcLane = (lane < 8) ? lane*8 : (lane < 16 ? (lane-8)*8 : 0);
    float vs = __shfl(ps, srcLane, 64);
    float vd = __shfl(pd, srcLane, 64);
    float myv;
    if (H == 8) myv = (lane < 8) ? vs : (lane < 16 ? vd : 0.f);
    else        myv = (lane == 0) ? ps : (lane == 1 ? pd : 0.f);
    const int kb = k >> 5, quad = (k >> 3) & 3, j = k & 7;
    if (lane < 16)
      Wmf[(((size_t)L*36 + 32 + kb)*64 + quad*16 + lane)*8 + j] = f2bs(myv);
  }
}

// ---------------- CSR build ----------------
__global__ void __launch_bounds__(256) hist_kernel(const int* __restrict__ ei, int* __restrict__ deg)
{
  int e = blockIdx.x*256 + threadIdx.x;
  if (e >= EP) return;
  int d = (e < EE) ? ei[EE + e] : e - EE;
  atomicAdd(&deg[d], 1);
}

__global__ void __launch_bounds__(256) scan1_kernel(const int* __restrict__ deg,
    int* __restrict__ rowStart, int* __restrict__ blockSums)
{
  __shared__ int buf[256];
  int i = blockIdx.x*256 + threadIdx.x;
  int v = (i < NN) ? deg[i] : 0;
  buf[threadIdx.x] = v;
  __syncthreads();
  for (int off = 1; off < 256; off <<= 1){
    int t = (threadIdx.x >= off) ? buf[threadIdx.x - off] : 0;
    __syncthreads();
    buf[threadIdx.x] += t;
    __syncthreads();
  }
  if (i < NN) rowStart[i] = buf[threadIdx.x] - v;
  if (threadIdx.x == 255) blockSums[blockIdx.x] = buf[255];
}

// merged: every block redundantly scans blockSums, then applies its offset
__global__ void __launch_bounds__(256) scan23_kernel(int* __restrict__ rowStart,
    const int* __restrict__ blockSums, int* __restrict__ cursor)
{
  __shared__ int buf[256];
  int v = (threadIdx.x < NB) ? blockSums[threadIdx.x] : 0;
  buf[threadIdx.x] = v;
  __syncthreads();
  for (int off = 1; off < 256; off <<= 1){
    int t = (threadIdx.x >= off) ? buf[threadIdx.x - off] : 0;
    __syncthreads();
    buf[threadIdx.x] += t;
    __syncthreads();
  }
  int myOff = (blockIdx.x == 0) ? 0 : buf[blockIdx.x - 1];
  int i = blockIdx.x*256 + threadIdx.x;
  if (i < NN){
    int val = rowStart[i] + myOff;
    rowStart[i] = val;
    cursor[i]   = val;
  }
  if (i == 0) rowStart[NN] = EP;
}

__global__ void __launch_bounds__(256) scatter_kernel(const int* __restrict__ ei,
    int* __restrict__ cursor, unsigned short* __restrict__ srcL)
{
  int e = blockIdx.x*256 + threadIdx.x;
  if (e >= EP) return;
  int s, d;
  if (e < EE){ s = ei[e]; d = ei[EE + e]; } else { s = d = e - EE; }
  int pos = atomicAdd(&cursor[d], 1);
  srcL[pos] = (unsigned short)s;
}

// ---------------- MFMA GEMM: h = x@W (bf16 out) + al dots via 9th col tile ----------------
// 64 rows/block, 4 waves, 16 rows/wave. A: x rows as bf16 frags; B: pre-packed Wmf in LDS.
template<bool XBF16, int H>
__global__ void __launch_bounds__(256) gemm_mfma_kernel(const void* __restrict__ Xv,
    const unsigned short* __restrict__ Wmf,
    unsigned short* __restrict__ Hout,
    float* __restrict__ alS, float* __restrict__ alD)
{
  __shared__ unsigned short wl[36*64*8];    // 36 KB = 2304 uint4
  const int tid = threadIdx.x;
  {
    const uint4* src = (const uint4*)Wmf;
    uint4* dst = (uint4*)wl;
    #pragma unroll
    for (int i = 0; i < 9; i++)             // 9*256 = 2304 uint4 — full copy
      dst[tid + i*256] = src[tid + i*256];
  }
  const int lane = tid & 63, wv = tid >> 6;
  const int r0 = blockIdx.x*64 + wv*16;
  const int m = lane & 15, quad = lane >> 4;
  const int row = r0 + m;
  const bool rowOK = row < NN;

  short8 a[4];
  if (XBF16){
    const short* Xb = (const short*)Xv;
    #pragma unroll
    for (int kb = 0; kb < 4; kb++){
      if (rowOK) a[kb] = *(const short8*)&Xb[(size_t)row*DD + kb*32 + quad*8];
      else       a[kb] = (short8){0,0,0,0,0,0,0,0};
    }
  } else {
    const float* Xf = (const float*)Xv;
    #pragma unroll
    for (int kb = 0; kb < 4; kb++){
      if (rowOK){
        float4 f0 = *(const float4*)&Xf[(size_t)row*DD + kb*32 + quad*8];
        float4 f1 = *(const float4*)&Xf[(size_t)row*DD + kb*32 + quad*8 + 4];
        union { short8 v; unsigned short u[8]; } cv;
        cv.u[0]=f2bs(f0.x); cv.u[1]=f2bs(f0.y); cv.u[2]=f2bs(f0.z); cv.u[3]=f2bs(f0.w);
        cv.u[4]=f2bs(f1.x); cv.u[5]=f2bs(f1.y); cv.u[6]=f2bs(f1.z); cv.u[7]=f2bs(f1.w);
        a[kb] = cv.v;
      } else a[kb] = (short8){0,0,0,0,0,0,0,0};
    }
  }
  __syncthreads();

  f32x4 acc[9];
  #pragma unroll
  for (int c = 0; c < 9; c++) acc[c] = (f32x4){0.f,0.f,0.f,0.f};
  #pragma unroll
  for (int c = 0; c < 9; c++){
    #pragma unroll
    for (int kb = 0; kb < 4; kb++){
      short8 b = *(const short8*)&wl[((c*4 + kb)*64 + lane)*8];
      acc[c] = __builtin_amdgcn_mfma_f32_16x16x32_bf16(a[kb], b, acc[c], 0, 0, 0);
    }
  }

  // h store: D layout col=lane&15, row=quad*4+reg  [m89/m91-verified]
  #pragma unroll
  for (int c = 0; c < 8; c++){
    #pragma unroll
    for (int r = 0; r < 4; r++){
      int rw = r0 + quad*4 + r;
      if (rw < NN) Hout[(size_t)rw*DD + c*16 + m] = f2bs(acc[c][r]);
    }
  }
  // al store from tile 8
  #pragma unroll
  for (int r = 0; r < 4; r++){
    int rw = r0 + quad*4 + r;
    if (rw < NN){
      float v = acc[8][r];
      if (H == 8){
        if (m < 8) alS[rw*8 + m]       = v;
        else       alD[rw*8 + (m - 8)] = v;
      } else {
        if (m == 0)      alS[rw] = v;
        else if (m == 1) alD[rw] = v;
      }
    }
  }
}

// ---------------- fused: per-dst softmax + gather-aggregate + bias + LN (+ELU) ----------------
// one wave per dst node; lane covers channels 2*lane, 2*lane+1.
// Round-6 proven structure: s uniform across wave per step -> alS row load is a
// BROADCAST (one 32B transaction), hB row load fully coalesced. 4x unroll for MLP.
template<int H, bool FINAL>
__global__ void __launch_bounds__(256) aggln_kernel(
    const int* __restrict__ rowStart, const unsigned short* __restrict__ srcL,
    const float* __restrict__ alS, const float* __restrict__ alD,
    const unsigned short* __restrict__ hB,
    const float* __restrict__ b, const float* __restrict__ g, const float* __restrict__ be,
    void* __restrict__ outv)
{
  const int lane = threadIdx.x & 63;
  const int d    = blockIdx.x*4 + (threadIdx.x >> 6);
  const int C    = DD / H;
  const int c0   = lane*2;
  const int hd   = c0 / C;
  const int start = rowStart[d], end = rowStart[d+1];
  const float aldv = alD[d*H + hd];

  float ssum = 0.f, a0 = 0.f, a1 = 0.f;
  for (int base = start; base < end; base += 64){
    const int cnt = min(64, end - base);
    int myS = (base + lane < end) ? (int)srcL[base + lane] : 0;
    int j = 0;
    for (; j + 4 <= cnt; j += 4){
      int s0 = __shfl(myS, j,   64);
      int s1 = __shfl(myS, j+1, 64);
      int s2 = __shfl(myS, j+2, 64);
      int s3 = __shfl(myS, j+3, 64);
      ushort2 h0 = *(const ushort2*)&hB[(size_t)s0*DD + c0];
      ushort2 h1 = *(const ushort2*)&hB[(size_t)s1*DD + c0];
      ushort2 h2 = *(const ushort2*)&hB[(size_t)s2*DD + c0];
      ushort2 h3 = *(const ushort2*)&hB[(size_t)s3*DD + c0];
      float e0 = alS[s0*H + hd] + aldv;
      float e1 = alS[s1*H + hd] + aldv;
      float e2 = alS[s2*H + hd] + aldv;
      float e3 = alS[s3*H + hd] + aldv;
      e0 = e0 > 0.f ? e0 : 0.2f*e0;
      e1 = e1 > 0.f ? e1 : 0.2f*e1;
      e2 = e2 > 0.f ? e2 : 0.2f*e2;
      e3 = e3 > 0.f ? e3 : 0.2f*e3;
      float w0 = __expf(fminf(e0, 80.f));
      float w1 = __expf(fminf(e1, 80.f));
      float w2 = __expf(fminf(e2, 80.f));
      float w3 = __expf(fminf(e3, 80.f));
      ssum += (w0 + w1) + (w2 + w3);
      a0 = fmaf(bfu(h0.x), w0, a0);  a1 = fmaf(bfu(h0.y), w0, a1);
      a0 = fmaf(bfu(h1.x), w1, a0);  a1 = fmaf(bfu(h1.y), w1, a1);
      a0 = fmaf(bfu(h2.x), w2, a0);  a1 = fmaf(bfu(h2.y), w2, a1);
      a0 = fmaf(bfu(h3.x), w3, a0);  a1 = fmaf(bfu(h3.y), w3, a1);
    }
    for (; j < cnt; j++){
      int s0 = __shfl(myS, j, 64);
      ushort2 h0 = *(const ushort2*)&hB[(size_t)s0*DD + c0];
      float e0 = alS[s0*H + hd] + aldv;
      e0 = e0 > 0.f ? e0 : 0.2f*e0;
      float w0 = __expf(fminf(e0, 80.f));
      ssum += w0;
      a0 = fmaf(bfu(h0.x), w0, a0);
      a1 = fmaf(bfu(h0.y), w0, a1);
    }
  }
  const float sinv = 1.f / ssum;

  // bias + LayerNorm across the wave's 128 channels
  float v0 = a0*sinv + b[c0], v1 = a1*sinv + b[c0+1];
  float s2 = v0 + v1;
  #pragma unroll
  for (int off = 32; off >= 1; off >>= 1) s2 += __shfl_xor(s2, off, 64);
  float mu = s2 * (1.0f/128.0f);
  float d0 = v0 - mu, d1 = v1 - mu;
  float q = d0*d0 + d1*d1;
  #pragma unroll
  for (int off = 32; off >= 1; off >>= 1) q += __shfl_xor(q, off, 64);
  float r = rsqrtf(q*(1.0f/128.0f) + 1e-5f);
  float y0 = d0*r*g[c0]   + be[c0];
  float y1 = d1*r*g[c0+1] + be[c0+1];
  if (FINAL){
    *(float2*)&((float*)outv)[(size_t)d*DD + c0] = make_float2(y0, y1);
  } else {
    y0 = y0 > 0.f ? y0 : __expf(y0) - 1.f;   // ELU
    y1 = y1 > 0.f ? y1 : __expf(y1) - 1.f;
    ushort2 o; o.x = f2bs(y0); o.y = f2bs(y1);
    *(ushort2*)&((unsigned short*)outv)[(size_t)d*DD + c0] = o;
  }
}

// ---------------- host-side layer driver ----------------
template<bool XBF16, int H, bool FINAL>
static void run_layer(const void* x, const unsigned short* WmfL,
                      const float* b, const float* g, const float* be,
                      const int* rowStart, const unsigned short* srcL,
                      unsigned short* hB, float* alS, float* alD,
                      void* outv, hipStream_t stream)
{
  gemm_mfma_kernel<XBF16, H><<<782, 256, 0, stream>>>(x, WmfL, hB, alS, alD);
  aggln_kernel<H, FINAL><<<12500, 256, 0, stream>>>(rowStart, srcL, alS, alD, hB,
                                                    b, g, be, outv);
}

extern "C" void kernel_launch(void* const* d_in, const int* in_sizes, int n_in,
                              void* d_out, int out_size, void* d_ws, size_t ws_size,
                              hipStream_t stream)
{
  // ws layout (~31.5 MB)
  char* w = (char*)d_ws;
  unsigned short* accB = (unsigned short*)w;     w += (size_t)NN*DD*2;   // 12.8 MB (bf16 x-next)
  unsigned short* hB   = (unsigned short*)w;     w += (size_t)NN*DD*2;   // 12.8 MB (bf16 h)
  float* alS      = (float*)w;                   w += (size_t)NN*8*4;    // 1.6 MB
  float* alD      = (float*)w;                   w += (size_t)NN*8*4;    // 1.6 MB
  unsigned short* Wmf = (unsigned short*)w;      w += (size_t)3*36*64*8*2; // 216 KB
  int*   deg      = (int*)w;                     w += (size_t)NN*4;      // 200 KB
  int*   rowStart = (int*)w;                     w += (size_t)(NN+1)*4;  // 200 KB
  int*   cursor   = (int*)w;                     w += (size_t)NN*4;      // 200 KB
  int*   blockSums= (int*)w;                     w += 1024;
  unsigned short* srcL = (unsigned short*)w;     w += (size_t)EP*2;      // 1.7 MB
  if (ws_size < (size_t)(w - (char*)d_ws)) return;

  const float* x  = (const float*)d_in[0];
  const int*   ei = (const int*)d_in[1];
  const float *W0=(const float*)d_in[2], *as0=(const float*)d_in[3], *ad0=(const float*)d_in[4];
  const float *b0=(const float*)d_in[5], *g0=(const float*)d_in[6], *be0=(const float*)d_in[7];
  const float *W1=(const float*)d_in[8], *as1=(const float*)d_in[9], *ad1=(const float*)d_in[10];
  const float *b1=(const float*)d_in[11],*g1=(const float*)d_in[12],*be1=(const float*)d_in[13];
  const float *W2=(const float*)d_in[14],*as2=(const float*)d_in[15],*ad2=(const float*)d_in[16];
  const float *b2=(const float*)d_in[17],*g2=(const float*)d_in[18],*be2=(const float*)d_in[19];

  prep_kernel<<<NB, 256, 0, stream>>>(W0, as0, ad0, W1, as1, ad1, W2, as2, ad2, Wmf, deg);
  hist_kernel<<<(EP + 255)/256, 256, 0, stream>>>(ei, deg);
  scan1_kernel<<<NB, 256, 0, stream>>>(deg, rowStart, blockSums);
  scan23_kernel<<<NB, 256, 0, stream>>>(rowStart, blockSums, cursor);
  scatter_kernel<<<(EP + 255)/256, 256, 0, stream>>>(ei, cursor, srcL);

  // layer 0: x = f32 input, 8 heads, ELU -> accB (bf16)
  run_layer<false, 8, false>(x,    Wmf,            b0, g0, be0,
                             rowStart, srcL, hB, alS, alD, accB, stream);
  // layer 1: x = accB (bf16), 8 heads, ELU -> accB
  run_layer<true, 8, false>(accB, Wmf + (size_t)36*64*8,   b1, g1, be1,
                             rowStart, srcL, hB, alS, alD, accB, stream);
  // layer 2: x = accB (bf16), 1 head, LN only -> d_out (f32)
  run_layer<true, 1, true>(accB, Wmf + (size_t)2*36*64*8,  b2, g2, be2,
                             rowStart, srcL, hB, alS, alD, d_out, stream);
}